// Round 7
// baseline (1545.385 us; speedup 1.0000x reference)
//
#include <hip/hip_runtime.h>
#include <math.h>

// Performer encoder on MI355X: B=4, S=4096, D=256, H=4, DH=64, L=4, M=266.
// bf16 MFMA everywhere; fp32 residual stream / LN stats / softmax logic.
// Round 7: fused full-row GEMM re-tiled 64-row/256-blk -> 16-row/1024-blk
// (4 blocks/CU instead of 1 — fixes the 9%-occupancy latency binding seen in r6).

#define WS_ALIGN(x) (((x) + 255) & ~(size_t)255)

#define DN 0.35355339059327373f      // 64^-0.25
#define DIAGC 0.0625f                 // 0.5 * 64^-0.5
#define RATIO 0.06131393394849658f    // 266^-0.5
#define FEPS 1e-4f

typedef __attribute__((__ext_vector_type__(8))) __bf16 bf16x8;
typedef __attribute__((__ext_vector_type__(4))) float f32x4;

__device__ __forceinline__ float wredsum(float v) {
    v += __shfl_xor(v, 32); v += __shfl_xor(v, 16); v += __shfl_xor(v, 8);
    v += __shfl_xor(v, 4);  v += __shfl_xor(v, 2);  v += __shfl_xor(v, 1);
    return v;
}
__device__ __forceinline__ float wredmax(float v) {
    v = fmaxf(v, __shfl_xor(v, 32)); v = fmaxf(v, __shfl_xor(v, 16));
    v = fmaxf(v, __shfl_xor(v, 8));  v = fmaxf(v, __shfl_xor(v, 4));
    v = fmaxf(v, __shfl_xor(v, 2));  v = fmaxf(v, __shfl_xor(v, 1));
    return v;
}

__device__ __forceinline__ unsigned short f2bf(float f) {
    unsigned u = __builtin_bit_cast(unsigned, f);
    return (unsigned short)((u + 0x7fffu + ((u >> 16) & 1u)) >> 16);
}
__device__ __forceinline__ float blo(unsigned x) { return __builtin_bit_cast(float, x << 16); }
__device__ __forceinline__ float bhi(unsigned x) { return __builtin_bit_cast(float, x & 0xffff0000u); }
__device__ __forceinline__ float sumsq8(uint4 u) {
    float s = 0.f;
    s += blo(u.x)*blo(u.x) + bhi(u.x)*bhi(u.x);
    s += blo(u.y)*blo(u.y) + bhi(u.y)*bhi(u.y);
    s += blo(u.z)*blo(u.z) + bhi(u.z)*bhi(u.z);
    s += blo(u.w)*blo(u.w) + bhi(u.w)*bhi(u.w);
    return s;
}

// ---------------- LayerNorm (fp32 in, fp32 or bf16 out) ----------------
template <bool OBF>
__global__ __launch_bounds__(256) void add_ln_kernel(
    const float* __restrict__ in, const float* __restrict__ pos,
    const float* __restrict__ g, const float* __restrict__ bta,
    float* __restrict__ outf, unsigned short* __restrict__ outb)
{
    int row = blockIdx.x, t = threadIdx.x;
    __shared__ float sred[4];
    float v = in[(size_t)row * 256 + t];
    if (pos) v += pos[(size_t)(row & 4095) * 256 + t];
    float s = wredsum(v);
    if ((t & 63) == 0) sred[t >> 6] = s;
    __syncthreads();
    float mean = (sred[0] + sred[1] + sred[2] + sred[3]) * (1.0f / 256.0f);
    float d = v - mean;
    __syncthreads();
    float sq = wredsum(d * d);
    if ((t & 63) == 0) sred[t >> 6] = sq;
    __syncthreads();
    float var = (sred[0] + sred[1] + sred[2] + sred[3]) * (1.0f / 256.0f);
    float y = d * rsqrtf(var + 1e-12f) * g[t] + bta[t];
    if (OBF) outb[(size_t)row * 256 + t] = f2bf(y);
    else     outf[(size_t)row * 256 + t] = y;
}

// ---------------- weight cast/transpose: fp32 [R][C] -> bf16 [C][R] ----------------
__global__ __launch_bounds__(256) void cast_transpose_kernel(
    const float* __restrict__ in, unsigned short* __restrict__ out, int R, int C)
{
    __shared__ float tile[32][33];
    size_t zo = (size_t)blockIdx.z * R * C;
    int c0 = blockIdx.x * 32, r0 = blockIdx.y * 32;
    int t = threadIdx.x, tc = t & 31, tr = t >> 5;
#pragma unroll
    for (int j = 0; j < 4; j++)
        tile[tr + j * 8][tc] = in[zo + (size_t)(r0 + tr + j * 8) * C + c0 + tc];
    __syncthreads();
#pragma unroll
    for (int j = 0; j < 4; j++) {
        int cc = tr + j * 8, rr = tc;
        out[zo + (size_t)(c0 + cc) * R + r0 + rr] = f2bf(tile[rr][cc]);
    }
}

// fp32 -> bf16 elementwise (n4 = count/4)
__global__ __launch_bounds__(256) void cast_row_kernel(
    const float4* __restrict__ in, ushort4* __restrict__ out, int n4)
{
    int i = blockIdx.x * 256 + threadIdx.x;
    if (i >= n4) return;
    float4 v = in[i];
    ushort4 o; o.x = f2bf(v.x); o.y = f2bf(v.y); o.z = f2bf(v.z); o.w = f2bf(v.w);
    out[i] = o;
}

// ---------------- fused QKV GEMM (N=768 over q|k|v), K=256 ----------------
__global__ __launch_bounds__(256) void qkv_kernel(
    const unsigned short* __restrict__ A,
    const unsigned short* __restrict__ Wqt, const unsigned short* __restrict__ Wkt,
    const unsigned short* __restrict__ Wvt,
    const float* __restrict__ bq, const float* __restrict__ bk, const float* __restrict__ bv,
    unsigned short* __restrict__ qbf, unsigned short* __restrict__ kbf,
    unsigned short* __restrict__ vT)
{
    __shared__ uint4 As[128][5];
    __shared__ uint4 Bs[64][5];
    const int K = 256;
    int t = threadIdx.x;
    int bm = blockIdx.y * 128, bn = blockIdx.x * 64;
    int grp = bn >> 8, lbn = bn & 255;
    const unsigned short* Bt = (grp == 0) ? Wqt : (grp == 1) ? Wkt : Wvt;
    const float* bias = (grp == 0) ? bq : (grp == 1) ? bk : bv;
    int w = t >> 6, l = t & 63, lm16 = l & 15, quad = l >> 4;
    int ar = t >> 1, ak = (t & 1) * 16;
    int br = t >> 2, bk2 = (t & 3) * 8;
    const unsigned short* Ab = A + (size_t)(bm + ar) * K + ak;
    const unsigned short* Bb = Bt + (size_t)(lbn + br) * K + bk2;
    f32x4 acc[2][4] = {};
    for (int k0 = 0; k0 < K; k0 += 32) {
        uint4 a0 = *(const uint4*)(Ab + k0);
        uint4 a1 = *(const uint4*)(Ab + k0 + 8);
        uint4 b0 = *(const uint4*)(Bb + k0);
        __syncthreads();
        As[ar][(ak >> 3)] = a0; As[ar][(ak >> 3) + 1] = a1;
        Bs[br][bk2 >> 3] = b0;
        __syncthreads();
        bf16x8 af[2], bfr[4];
        af[0] = *(const bf16x8*)&As[w * 32 + lm16][quad];
        af[1] = *(const bf16x8*)&As[w * 32 + 16 + lm16][quad];
#pragma unroll
        for (int j = 0; j < 4; j++) bfr[j] = *(const bf16x8*)&Bs[j * 16 + lm16][quad];
#pragma unroll
        for (int i = 0; i < 2; i++)
#pragma unroll
            for (int j = 0; j < 4; j++)
                acc[i][j] = __builtin_amdgcn_mfma_f32_16x16x32_bf16(af[i], bfr[j], acc[i][j], 0, 0, 0);
    }
#pragma unroll
    for (int i = 0; i < 2; i++)
#pragma unroll
        for (int j = 0; j < 4; j++) {
            int lcol = lbn + j * 16 + lm16;
            float bs = bias[lcol];
            int h = lcol >> 6, e = lcol & 63;
#pragma unroll
            for (int r = 0; r < 4; r++) {
                int row = bm + w * 32 + i * 16 + quad * 4 + r;
                int b = row >> 12, s = row & 4095;
                float v = acc[i][j][r] + bs;
                if (grp == 0)
                    qbf[((size_t)((b << 2) + h) * 4096 + s) * 64 + e] = f2bf(v);
                else if (grp == 1)
                    kbf[((size_t)((b << 2) + h) * 4096 + s) * 64 + e] = f2bf(v);
                else
                    vT[((size_t)((b << 2) + h) * 64 + e) * 4096 + s] = f2bf(v);
            }
        }
}

// ---------------- FFN1 GEMM: gelu(tanh) epilogue, bf16 out ----------------
__global__ __launch_bounds__(256) void ffn1_kernel(
    const unsigned short* __restrict__ A, const unsigned short* __restrict__ Bt,
    const float* __restrict__ bias, unsigned short* __restrict__ Cb, int N, int K)
{
    __shared__ uint4 As[128][5];
    __shared__ uint4 Bs[64][5];
    int t = threadIdx.x;
    int bm = blockIdx.y * 128, bn = blockIdx.x * 64;
    int w = t >> 6, l = t & 63, lm16 = l & 15, quad = l >> 4;
    int ar = t >> 1, ak = (t & 1) * 16;
    int br = t >> 2, bk = (t & 3) * 8;
    const unsigned short* Ab = A + (size_t)(bm + ar) * K + ak;
    const unsigned short* Bb = Bt + (size_t)(bn + br) * K + bk;
    f32x4 acc[2][4] = {};
    for (int k0 = 0; k0 < K; k0 += 32) {
        uint4 a0 = *(const uint4*)(Ab + k0);
        uint4 a1 = *(const uint4*)(Ab + k0 + 8);
        uint4 b0 = *(const uint4*)(Bb + k0);
        __syncthreads();
        As[ar][(ak >> 3)] = a0; As[ar][(ak >> 3) + 1] = a1;
        Bs[br][bk >> 3] = b0;
        __syncthreads();
        bf16x8 af[2], bfr[4];
        af[0] = *(const bf16x8*)&As[w * 32 + lm16][quad];
        af[1] = *(const bf16x8*)&As[w * 32 + 16 + lm16][quad];
#pragma unroll
        for (int j = 0; j < 4; j++) bfr[j] = *(const bf16x8*)&Bs[j * 16 + lm16][quad];
#pragma unroll
        for (int i = 0; i < 2; i++)
#pragma unroll
            for (int j = 0; j < 4; j++)
                acc[i][j] = __builtin_amdgcn_mfma_f32_16x16x32_bf16(af[i], bfr[j], acc[i][j], 0, 0, 0);
    }
#pragma unroll
    for (int i = 0; i < 2; i++)
#pragma unroll
        for (int j = 0; j < 4; j++) {
            int col = bn + j * 16 + lm16;
            float bsv = bias[col];
#pragma unroll
            for (int r = 0; r < 4; r++) {
                int row = bm + w * 32 + i * 16 + quad * 4 + r;
                float v = acc[i][j][r] + bsv;
                float inner = 0.7978845608028654f * (v + 0.044715f * v * v * v);
                float gl = 0.5f * v * (1.0f + tanhf(inner));
                Cb[(size_t)row * N + col] = f2bf(gl);
            }
        }
}

// ---------------- fused full-row GEMM: 16 rows x N=256 per block (grid M/16) ----------
// Wave w computes the same 16 rows x cols [w*64, w*64+64). LN stats via LDS cross-wave.
// EPI 0: +bias +resid(xio); write xio fp32; LayerNorm -> outb bf16
// EPI 1: +bias +resid(xio); write xio fp32; plain bf16 cast -> outb
// EPI 2: pooling: alpha[row] = exp(sum_col tanh(v+bias)*p2w + p2b) * mask[row]
template <int EPI>
__global__ __launch_bounds__(256) void gemm_row16_kernel(
    const unsigned short* __restrict__ A, const unsigned short* __restrict__ Bt,
    const float* __restrict__ bias, float* __restrict__ xio,
    const float* __restrict__ lng, const float* __restrict__ lnb,
    unsigned short* __restrict__ outb,
    const float* __restrict__ p2w, const float* __restrict__ p2b,
    const float* __restrict__ mask, float* __restrict__ alphab, int K)
{
    __shared__ uint4 As[16][5];
    __shared__ uint4 Bs[256][5];
    __shared__ float red[4][16];
    __shared__ float red2[4][16];
    int t = threadIdx.x;
    int bm = blockIdx.x * 16;
    int w = t >> 6, l = t & 63, lm16 = l & 15, quad = l >> 4;
    int brow = t >> 2, bj = t & 3;
    f32x4 acc[4] = {};
    for (int k0 = 0; k0 < K; k0 += 32) {
        uint4 a = {0, 0, 0, 0};
        if (t < 64) a = *(const uint4*)(A + (size_t)(bm + (t >> 2)) * K + k0 + (t & 3) * 8);
        uint4 b[4];
#pragma unroll
        for (int i = 0; i < 4; i++)
            b[i] = *(const uint4*)(Bt + (size_t)(brow + i * 64) * K + k0 + bj * 8);
        __syncthreads();
        if (t < 64) As[t >> 2][t & 3] = a;
#pragma unroll
        for (int i = 0; i < 4; i++) Bs[brow + i * 64][bj] = b[i];
        __syncthreads();
        bf16x8 af = *(const bf16x8*)&As[lm16][quad];
#pragma unroll
        for (int j = 0; j < 4; j++) {
            bf16x8 bfv = *(const bf16x8*)&Bs[w * 64 + j * 16 + lm16][quad];
            acc[j] = __builtin_amdgcn_mfma_f32_16x16x32_bf16(af, bfv, acc[j], 0, 0, 0);
        }
    }
    int colbase = w * 64;
    if (EPI == 2) {
        float rs[4] = {0.f, 0.f, 0.f, 0.f};
#pragma unroll
        for (int j = 0; j < 4; j++) {
            int col = colbase + j * 16 + lm16;
            float bs = bias[col], pw = p2w[col];
#pragma unroll
            for (int r = 0; r < 4; r++)
                rs[r] += tanhf(acc[j][r] + bs) * pw;
        }
#pragma unroll
        for (int m2 = 1; m2 <= 8; m2 <<= 1)
#pragma unroll
            for (int r = 0; r < 4; r++) rs[r] += __shfl_xor(rs[r], m2);
        if (lm16 == 0) {
#pragma unroll
            for (int r = 0; r < 4; r++) red[w][quad * 4 + r] = rs[r];
        }
        __syncthreads();
        if (t < 16) {
            float sc = red[0][t] + red[1][t] + red[2][t] + red[3][t] + p2b[0];
            int row = bm + t;
            alphab[row] = expf(sc) * mask[row];
        }
        return;
    }
    float rs[4] = {0.f, 0.f, 0.f, 0.f};
#pragma unroll
    for (int j = 0; j < 4; j++) {
        int col = colbase + j * 16 + lm16;
        float bs = bias[col];
#pragma unroll
        for (int r = 0; r < 4; r++) {
            int row = bm + quad * 4 + r;
            float v = acc[j][r] + bs + xio[(size_t)row * 256 + col];
            acc[j][r] = v;
            rs[r] += v;
        }
    }
    float mean[4], rstd[4];
    if (EPI == 0) {
#pragma unroll
        for (int m2 = 1; m2 <= 8; m2 <<= 1)
#pragma unroll
            for (int r = 0; r < 4; r++) rs[r] += __shfl_xor(rs[r], m2);
        if (lm16 == 0) {
#pragma unroll
            for (int r = 0; r < 4; r++) red[w][quad * 4 + r] = rs[r];
        }
        __syncthreads();
        float vs[4] = {0.f, 0.f, 0.f, 0.f};
#pragma unroll
        for (int r = 0; r < 4; r++) {
            int rr = quad * 4 + r;
            mean[r] = (red[0][rr] + red[1][rr] + red[2][rr] + red[3][rr]) * (1.0f / 256.0f);
        }
#pragma unroll
        for (int j = 0; j < 4; j++)
#pragma unroll
            for (int r = 0; r < 4; r++) {
                float d = acc[j][r] - mean[r];
                vs[r] += d * d;
            }
#pragma unroll
        for (int m2 = 1; m2 <= 8; m2 <<= 1)
#pragma unroll
            for (int r = 0; r < 4; r++) vs[r] += __shfl_xor(vs[r], m2);
        if (lm16 == 0) {
#pragma unroll
            for (int r = 0; r < 4; r++) red2[w][quad * 4 + r] = vs[r];
        }
        __syncthreads();
#pragma unroll
        for (int r = 0; r < 4; r++) {
            int rr = quad * 4 + r;
            rstd[r] = rsqrtf((red2[0][rr] + red2[1][rr] + red2[2][rr] + red2[3][rr])
                             * (1.0f / 256.0f) + 1e-12f);
        }
    }
#pragma unroll
    for (int j = 0; j < 4; j++) {
        int col = colbase + j * 16 + lm16;
        float g  = (EPI == 0) ? lng[col] : 0.f;
        float bb = (EPI == 0) ? lnb[col] : 0.f;
#pragma unroll
        for (int r = 0; r < 4; r++) {
            int row = bm + quad * 4 + r;
            float v = acc[j][r];
            xio[(size_t)row * 256 + col] = v;
            float y = (EPI == 0) ? ((v - mean[r]) * rstd[r] * g + bb) : v;
            outb[(size_t)row * 256 + col] = f2bf(y);
        }
    }
}

// ---------------- phi row kernel: 64 s x 272 m per block ----------------
// MODE 0 (q): dash -> row max -> exp -> qp bf16 [bh][s][272]; denom = qp.ksum
// MODE 1 (k): dash -> block max -> pmax[bh*64 + blk]
template <int MODE>
__global__ __launch_bounds__(256) void phi_row_kernel(
    const unsigned short* __restrict__ xbf, const unsigned short* __restrict__ projbf,
    const float* __restrict__ ksum, unsigned short* __restrict__ qp,
    float* __restrict__ denomb, float* __restrict__ pmax)
{
    __shared__ uint4 As[64][9];
    __shared__ uint4 Bs[272][9];
    __shared__ float diag_s[64];
    __shared__ float ks_s[272];
    __shared__ float sred[4];
    int t = threadIdx.x;
    int s0 = blockIdx.x * 64;
    int bh = blockIdx.y;
    {
        int arow = t >> 2, akoff = (t & 3) * 16;
        const uint4* ga = (const uint4*)(xbf + ((size_t)bh * 4096 + s0 + arow) * 64 + akoff);
        uint4 u0 = ga[0], u1 = ga[1];
        As[arow][(akoff >> 3)] = u0; As[arow][(akoff >> 3) + 1] = u1;
        float ss = sumsq8(u0) + sumsq8(u1);
        ss += __shfl_xor(ss, 1); ss += __shfl_xor(ss, 2);
        if ((t & 3) == 0) diag_s[arow] = DIAGC * ss;
        uint4 zero = {0, 0, 0, 0};
        for (int row = t; row < 272; row += 256) {
            const uint4* gp = (const uint4*)(projbf + (size_t)row * 64);
            bool bv = row < 266;
#pragma unroll
            for (int i2 = 0; i2 < 8; i2++) Bs[row][i2] = bv ? gp[i2] : zero;
        }
        if (MODE == 0) {
            ks_s[t] = ksum[bh * 272 + t];
            if (t < 16) ks_s[256 + t] = ksum[bh * 272 + 256 + t];
        }
    }
    __syncthreads();
    int w = t >> 6, l = t & 63, lm16 = l & 15, quad = l >> 4;
    f32x4 acc[17] = {};
#pragma unroll
    for (int ks = 0; ks < 2; ks++) {
        bf16x8 af = *(const bf16x8*)&As[w * 16 + lm16][ks * 4 + quad];
#pragma unroll
        for (int j = 0; j < 17; j++) {
            bf16x8 bfv = *(const bf16x8*)&Bs[j * 16 + lm16][ks * 4 + quad];
            acc[j] = __builtin_amdgcn_mfma_f32_16x16x32_bf16(af, bfv, acc[j], 0, 0, 0);
        }
    }
    int rloc = w * 16 + quad * 4;
    float dg[4];
#pragma unroll
    for (int r = 0; r < 4; r++) dg[r] = diag_s[rloc + r];
    if (MODE == 1) {
        float kmax = -1e30f;
#pragma unroll
        for (int j = 0; j < 17; j++) {
            int m = j * 16 + lm16;
            bool valid = m < 266;
#pragma unroll
            for (int r = 0; r < 4; r++)
                if (valid) kmax = fmaxf(kmax, acc[j][r] * DN - dg[r]);
        }
        kmax = wredmax(kmax);
        if (l == 0) sred[w] = kmax;
        __syncthreads();
        if (t == 0)
            pmax[(size_t)bh * 64 + blockIdx.x] =
                fmaxf(fmaxf(sred[0], sred[1]), fmaxf(sred[2], sred[3]));
        return;
    }
    float vmax[4] = {-1e30f, -1e30f, -1e30f, -1e30f};
#pragma unroll
    for (int j = 0; j < 17; j++) {
        int m = j * 16 + lm16;
        bool valid = m < 266;
#pragma unroll
        for (int r = 0; r < 4; r++) {
            float v = acc[j][r] * DN - dg[r];
            acc[j][r] = v;
            if (valid) vmax[r] = fmaxf(vmax[r], v);
        }
    }
#pragma unroll
    for (int m2 = 1; m2 <= 8; m2 <<= 1)
#pragma unroll
        for (int r = 0; r < 4; r++) vmax[r] = fmaxf(vmax[r], __shfl_xor(vmax[r], m2));
    float den[4] = {0.f, 0.f, 0.f, 0.f};
#pragma unroll
    for (int j = 0; j < 17; j++) {
        int m = j * 16 + lm16;
        bool valid = m < 266;
#pragma unroll
        for (int r = 0; r < 4; r++) {
            float e = valid ? RATIO * (expf(acc[j][r] - vmax[r]) + FEPS) : 0.f;
            qp[((size_t)bh * 4096 + s0 + rloc + r) * 272 + m] = f2bf(e);
            den[r] += e * ks_s[m];
        }
    }
#pragma unroll
    for (int m2 = 1; m2 <= 8; m2 <<= 1)
#pragma unroll
        for (int r = 0; r < 4; r++) den[r] += __shfl_xor(den[r], m2);
    if (lm16 == 0) {
#pragma unroll
        for (int r = 0; r < 4; r++)
            denomb[(size_t)bh * 4096 + s0 + rloc + r] = den[r];
    }
}

__global__ __launch_bounds__(256) void reduce_max_kernel(
    const float* __restrict__ pmax, float* __restrict__ stab, int n)
{
    __shared__ float sred[4];
    int t = threadIdx.x;
    float m = -1e30f;
    for (int i = t; i < n; i += 256) m = fmaxf(m, pmax[i]);
    m = wredmax(m);
    if ((t & 63) == 0) sred[t >> 6] = m;
    __syncthreads();
    if (t == 0) stab[0] = fmaxf(fmaxf(sred[0], sred[1]), fmaxf(sred[2], sred[3]));
}

// ---------------- fused ctx: dash -> exp -> (LDS transform) -> ctx MFMA + ksum ----------------
__global__ __launch_bounds__(256) void ctx_fused_kernel(
    const unsigned short* __restrict__ kbf, const unsigned short* __restrict__ vT,
    const unsigned short* __restrict__ projbf, const float* __restrict__ stab,
    float* __restrict__ ksum, float* __restrict__ ctxT)
{
    __shared__ uint4 Ap[64][9];               // proj tile [m_loc][k]
    __shared__ uint4 Ks[64][9];               // k chunk   [s_loc][k]
    __shared__ uint4 Vs[64][9];               // v chunk   [e][s_loc]
    __shared__ unsigned short kp_s[64][72];   // kp tile   [m_loc][s_loc]
    __shared__ float diag_s[64];
    int t = threadIdx.x;
    int m0 = blockIdx.x * 64;
    int bh = blockIdx.y;
    int sb = blockIdx.z * 512;
    int w = t >> 6, l = t & 63, lm16 = l & 15, quad = l >> 4;
    {
        int row = t >> 2, koff = (t & 3) * 16;
        uint4 zero = {0, 0, 0, 0};
        bool bv = (m0 + row) < 266;
        const uint4* gp = (const uint4*)(projbf + (size_t)(m0 + row) * 64 + koff);
        Ap[row][(koff >> 3)] = bv ? gp[0] : zero;
        Ap[row][(koff >> 3) + 1] = bv ? gp[1] : zero;
    }
    float st = stab[0];
    f32x4 accc[4] = {};
    float ksacc[4] = {0.f, 0.f, 0.f, 0.f};
    int srow = t >> 2, skoff = (t & 3) * 16;
    for (int kc = 0; kc < 8; kc++) {
        int sc = sb + kc * 64;
        const uint4* gk = (const uint4*)(kbf + ((size_t)bh * 4096 + sc + srow) * 64 + skoff);
        uint4 k0 = gk[0], k1 = gk[1];
        const uint4* gv = (const uint4*)(vT + ((size_t)bh * 64 + srow) * 4096 + sc + skoff);
        uint4 v0 = gv[0], v1 = gv[1];
        __syncthreads();
        Ks[srow][(skoff >> 3)] = k0; Ks[srow][(skoff >> 3) + 1] = k1;
        Vs[srow][(skoff >> 3)] = v0; Vs[srow][(skoff >> 3) + 1] = v1;
        float ss = sumsq8(k0) + sumsq8(k1);
        ss += __shfl_xor(ss, 1); ss += __shfl_xor(ss, 2);
        if ((t & 3) == 0) diag_s[srow] = DIAGC * ss;
        __syncthreads();
        f32x4 accd[4] = {};
#pragma unroll
        for (int ks = 0; ks < 2; ks++) {
            bf16x8 af = *(const bf16x8*)&Ap[w * 16 + lm16][ks * 4 + quad];
#pragma unroll
            for (int j = 0; j < 4; j++) {
                bf16x8 bfv = *(const bf16x8*)&Ks[j * 16 + lm16][ks * 4 + quad];
                accd[j] = __builtin_amdgcn_mfma_f32_16x16x32_bf16(af, bfv, accd[j], 0, 0, 0);
            }
        }
        int mbase = m0 + w * 16 + quad * 4;
#pragma unroll
        for (int j = 0; j < 4; j++) {
            int s_loc = j * 16 + lm16;
            float dgv = diag_s[s_loc];
#pragma unroll
            for (int r = 0; r < 4; r++) {
                float v = accd[j][r] * DN - dgv;
                float e = (mbase + r < 266) ? RATIO * (expf(v - st) + FEPS) : 0.f;
                kp_s[w * 16 + quad * 4 + r][s_loc] = f2bf(e);
                ksacc[r] += e;
            }
        }
        __syncthreads();
#pragma unroll
        for (int ks = 0; ks < 2; ks++) {
            bf16x8 af = *(const bf16x8*)&Vs[w * 16 + lm16][ks * 4 + quad];
#pragma unroll
            for (int jt = 0; jt < 4; jt++) {
                bf16x8 bfv = *(const bf16x8*)&kp_s[jt * 16 + lm16][ks * 32 + quad * 8];
                accc[jt] = __builtin_amdgcn_mfma_f32_16x16x32_bf16(af, bfv, accc[jt], 0, 0, 0);
            }
        }
    }
#pragma unroll
    for (int r = 0; r < 4; r++) {
        float v = ksacc[r];
        v += __shfl_xor(v, 1); v += __shfl_xor(v, 2);
        v += __shfl_xor(v, 4); v += __shfl_xor(v, 8);
        if (lm16 == 0) {
            int m = m0 + w * 16 + quad * 4 + r;
            if (m < 272) atomicAdd(&ksum[bh * 272 + m], v);
        }
    }
#pragma unroll
    for (int jt = 0; jt < 4; jt++) {
        int m = m0 + jt * 16 + lm16;
        if (m >= 272) continue;
#pragma unroll
        for (int r = 0; r < 4; r++) {
            int e = w * 16 + quad * 4 + r;
            atomicAdd(&ctxT[((size_t)bh * 64 + e) * 272 + m], accc[jt][r]);
        }
    }
}

// ---------------- attn MFMA: out = (qp @ ctxT^T)/denom -> abf [b][s][h*64+e] ----------------
__global__ __launch_bounds__(256) void attn_mfma_kernel(
    const unsigned short* __restrict__ qp, const unsigned short* __restrict__ ctxTbf,
    const float* __restrict__ denomb, unsigned short* __restrict__ abf)
{
    __shared__ uint4 As[128][5];
    __shared__ uint4 Bs[64][5];
    int t = threadIdx.x;
    int s0 = blockIdx.x * 128;
    int bh = blockIdx.y; int b = bh >> 2, h = bh & 3;
    int w = t >> 6, l = t & 63, lm16 = l & 15, quad = l >> 4;
    int ar = t >> 1, ak = (t & 1) * 16;
    int br = t >> 2, bk = (t & 3) * 8;
    const unsigned short* Ab = qp + ((size_t)bh * 4096 + s0 + ar) * 272 + ak;
    const unsigned short* Bb = ctxTbf + ((size_t)bh * 64 + br) * 272 + bk;
    uint4 zero = {0, 0, 0, 0};
    f32x4 acc[2][4] = {};
    for (int k0 = 0; k0 < 272; k0 += 32) {
        uint4 a0 = (k0 + ak < 272)     ? *(const uint4*)(Ab + k0)     : zero;
        uint4 a1 = (k0 + ak + 8 < 272) ? *(const uint4*)(Ab + k0 + 8) : zero;
        uint4 b0 = (k0 + bk < 272)     ? *(const uint4*)(Bb + k0)     : zero;
        __syncthreads();
        As[ar][(ak >> 3)] = a0; As[ar][(ak >> 3) + 1] = a1;
        Bs[br][bk >> 3] = b0;
        __syncthreads();
        bf16x8 af[2], bfr[4];
        af[0] = *(const bf16x8*)&As[w * 32 + lm16][quad];
        af[1] = *(const bf16x8*)&As[w * 32 + 16 + lm16][quad];
#pragma unroll
        for (int j = 0; j < 4; j++) bfr[j] = *(const bf16x8*)&Bs[j * 16 + lm16][quad];
#pragma unroll
        for (int i = 0; i < 2; i++)
#pragma unroll
            for (int j = 0; j < 4; j++)
                acc[i][j] = __builtin_amdgcn_mfma_f32_16x16x32_bf16(af[i], bfr[j], acc[i][j], 0, 0, 0);
    }
#pragma unroll
    for (int i = 0; i < 2; i++)
#pragma unroll
        for (int j = 0; j < 4; j++)
#pragma unroll
            for (int r = 0; r < 4; r++) {
                int s = s0 + w * 32 + i * 16 + quad * 4 + r;
                float v = acc[i][j][r] / denomb[(size_t)bh * 4096 + s];
                int e = j * 16 + lm16;
                abf[((size_t)(b * 4096 + s)) * 256 + h * 64 + e] = f2bf(v);
            }
}

// ---------------- pooling tail ----------------
__global__ __launch_bounds__(256) void pool_denom_kernel(
    const float* __restrict__ alpha, float* __restrict__ denomb)
{
    __shared__ float sred[4];
    int b = blockIdx.x, t = threadIdx.x;
    float p = 0.f;
    for (int s = t; s < 4096; s += 256) p += alpha[b * 4096 + s];
    p = wredsum(p);
    if ((t & 63) == 0) sred[t >> 6] = p;
    __syncthreads();
    if (t == 0) denomb[b] = sred[0] + sred[1] + sred[2] + sred[3] + 1e-8f;
}

__global__ __launch_bounds__(256) void pool_out_kernel(
    const float* __restrict__ x, const float* __restrict__ alpha,
    const float* __restrict__ denomb, float* __restrict__ out)
{
    int b = blockIdx.x, chunk = blockIdx.y, t = threadIdx.x;
    float inv = 1.0f / denomb[b];
    float acc = 0.f;
    int s0 = chunk * 128;
    for (int s = s0; s < s0 + 128; s++)
        acc += x[((size_t)(b << 12) + s) * 256 + t] * alpha[(b << 12) + s];
    atomicAdd(&out[b * 256 + t], acc * inv);
}

extern "C" void kernel_launch(void* const* d_in, const int* in_sizes, int n_in,
                              void* d_out, int out_size, void* d_ws, size_t ws_size,
                              hipStream_t stream)
{
    const float* input_embs = (const float*)d_in[0];
    const float* mask  = (const float*)d_in[1];
    const float* pos   = (const float*)d_in[2];
    const float* ln_g  = (const float*)d_in[3];
    const float* ln_b  = (const float*)d_in[4];
    const float* proj  = (const float*)d_in[5];
    const float* Wq = (const float*)d_in[6];  const float* bq = (const float*)d_in[7];
    const float* Wk = (const float*)d_in[8];  const float* bk = (const float*)d_in[9];
    const float* Wv = (const float*)d_in[10]; const float* bv = (const float*)d_in[11];
    const float* Wo = (const float*)d_in[12]; const float* bo = (const float*)d_in[13];
    const float* ln1g = (const float*)d_in[14]; const float* ln1b = (const float*)d_in[15];
    const float* W1 = (const float*)d_in[16]; const float* b1 = (const float*)d_in[17];
    const float* W2 = (const float*)d_in[18]; const float* b2 = (const float*)d_in[19];
    const float* ln2g = (const float*)d_in[20]; const float* ln2b = (const float*)d_in[21];
    const float* p1w = (const float*)d_in[22]; const float* p1b = (const float*)d_in[23];
    const float* p2w = (const float*)d_in[24]; const float* p2b = (const float*)d_in[25];
    float* out = (float*)d_out;
    char* ws = (char*)d_ws;

    size_t off = 0;
    auto alloc = [&](size_t bytes) { size_t o = off; off += WS_ALIGN(bytes); return o; };
    float* xbuf = (float*)(ws + alloc(16384ull * 256 * 4));
    unsigned short* hbf = (unsigned short*)(ws + alloc(16384ull * 256 * 2));   // ln-out / attn-out
    unsigned short* qbf = (unsigned short*)(ws + alloc(16384ull * 256 * 2));
    unsigned short* kbf = (unsigned short*)(ws + alloc(16384ull * 256 * 2));
    unsigned short* vT  = (unsigned short*)(ws + alloc(16384ull * 256 * 2));
    unsigned short* qp  = (unsigned short*)(ws + alloc(16ull * 4096 * 272 * 2)); // alias: FFN mid
    size_t ksum_off = alloc(16ull * 272 * 4);
    float* ksum = (float*)(ws + ksum_off);
    float* ctxT = (float*)(ws + alloc(16ull * 64 * 272 * 4));      // adjacent to ksum (one memset)
    size_t zero_bytes = WS_ALIGN(16ull * 272 * 4) + WS_ALIGN(16ull * 64 * 272 * 4);
    unsigned short* ctxTbf = (unsigned short*)(ws + alloc(16ull * 64 * 272 * 2));
    float* denomb = (float*)(ws + alloc(65536ull * 4));
    float* pmaxb = (float*)(ws + alloc(1024ull * 4));
    float* stabb = (float*)(ws + alloc(256));
    float* alphab = (float*)(ws + alloc(16384ull * 4));
    float* pdenom = (float*)(ws + alloc(256));
    unsigned short* Wqt = (unsigned short*)(ws + alloc(4ull * 65536 * 2));
    unsigned short* Wkt = (unsigned short*)(ws + alloc(4ull * 65536 * 2));
    unsigned short* Wvt = (unsigned short*)(ws + alloc(4ull * 65536 * 2));
    unsigned short* Wot = (unsigned short*)(ws + alloc(4ull * 65536 * 2));
    unsigned short* W1t = (unsigned short*)(ws + alloc(4ull * 262144 * 2));
    unsigned short* W2t = (unsigned short*)(ws + alloc(4ull * 262144 * 2));
    unsigned short* projbf = (unsigned short*)(ws + alloc(4ull * 17024 * 2));
    unsigned short* p1t = (unsigned short*)(ws + alloc(65536ull * 2));
    unsigned short* midbf = qp;   // FFN intermediate aliases qp (disjoint lifetimes)
    unsigned short* abf = hbf;
    // total ~95 MB (< 256 MiB)

    // ---- weight casts (all layers up front) ----
    cast_transpose_kernel<<<dim3(8, 8, 4), 256, 0, stream>>>(Wq, Wqt, 256, 256);
    cast_transpose_kernel<<<dim3(8, 8, 4), 256, 0, stream>>>(Wk, Wkt, 256, 256);
    cast_transpose_kernel<<<dim3(8, 8, 4), 256, 0, stream>>>(Wv, Wvt, 256, 256);
    cast_transpose_kernel<<<dim3(8, 8, 4), 256, 0, stream>>>(Wo, Wot, 256, 256);
    cast_transpose_kernel<<<dim3(32, 8, 4), 256, 0, stream>>>(W1, W1t, 256, 1024);
    cast_transpose_kernel<<<dim3(8, 32, 4), 256, 0, stream>>>(W2, W2t, 1024, 256);
    cast_transpose_kernel<<<dim3(8, 8, 1), 256, 0, stream>>>(p1w, p1t, 256, 256);
    cast_row_kernel<<<67, 256, 0, stream>>>((const float4*)proj, (ushort4*)projbf, 17024);

    // ---- x = LN(input + pos); hbf = LN1_0(x) ----
    add_ln_kernel<false><<<16384, 256, 0, stream>>>(input_embs, pos, ln_g, ln_b, xbuf, nullptr);
    add_ln_kernel<true><<<16384, 256, 0, stream>>>(xbuf, nullptr, ln1g, ln1b, nullptr, hbf);

    for (int i = 0; i < 4; i++) {
        const unsigned short* pj = projbf + (size_t)i * 17024;
        // QKV fused
        qkv_kernel<<<dim3(12, 128), 256, 0, stream>>>(hbf,
            Wqt + (size_t)i * 65536, Wkt + (size_t)i * 65536, Wvt + (size_t)i * 65536,
            bq + i * 256, bk + i * 256, bv + i * 256, qbf, kbf, vT);
        // k stabilizer: dash max (row tiling) -> global reduce
        phi_row_kernel<1><<<dim3(64, 16), 256, 0, stream>>>(kbf, pj, nullptr, nullptr, nullptr, pmaxb);
        reduce_max_kernel<<<1, 256, 0, stream>>>(pmaxb, stabb, 1024);
        // fused k-exp + ksum + ctx
        hipMemsetAsync(ws + ksum_off, 0, zero_bytes, stream);
        ctx_fused_kernel<<<dim3(5, 16, 8), 256, 0, stream>>>(kbf, vT, pj, stabb, ksum, ctxT);
        // q-side fully fused (dash + rowmax + exp + denom)
        phi_row_kernel<0><<<dim3(64, 16), 256, 0, stream>>>(qbf, pj, ksum, qp, denomb, nullptr);
        // attn out
        cast_row_kernel<<<272, 256, 0, stream>>>((const float4*)ctxT, (ushort4*)ctxTbf, 16 * 64 * 272 / 4);
        attn_mfma_kernel<<<dim3(32, 16), 256, 0, stream>>>(qp, ctxTbf, denomb, abf);
        // Wo + residual + LN2 fused (16-row blocks, grid 1024)
        gemm_row16_kernel<0><<<1024, 256, 0, stream>>>(abf, Wot + (size_t)i * 65536,
            bo + i * 256, xbuf, ln2g + i * 256, ln2b + i * 256, hbf,
            nullptr, nullptr, nullptr, nullptr, 256);
        // FFN
        ffn1_kernel<<<dim3(16, 128), 256, 0, stream>>>(hbf, W1t + (size_t)i * 262144,
            b1 + i * 1024, midbf, 1024, 256);
        if (i < 3)
            gemm_row16_kernel<0><<<1024, 256, 0, stream>>>(midbf, W2t + (size_t)i * 262144,
                b2 + i * 256, xbuf, ln1g + (i + 1) * 256, ln1b + (i + 1) * 256, hbf,
                nullptr, nullptr, nullptr, nullptr, 1024);
        else
            gemm_row16_kernel<1><<<1024, 256, 0, stream>>>(midbf, W2t + (size_t)i * 262144,
                b2 + i * 256, xbuf, nullptr, nullptr, hbf,
                nullptr, nullptr, nullptr, nullptr, 1024);
    }

    // ---- attention pooling (score fused into GEMM) ----
    gemm_row16_kernel<2><<<1024, 256, 0, stream>>>(hbf, p1t, p1b, nullptr, nullptr, nullptr,
        nullptr, p2w, p2b, mask, alphab, 256);
    pool_denom_kernel<<<4, 256, 0, stream>>>(alphab, pdenom);
    hipMemsetAsync(d_out, 0, (size_t)out_size * sizeof(float), stream);
    pool_out_kernel<<<dim3(4, 32), 256, 0, stream>>>(xbuf, alphab, pdenom, out);
}

// Round 8
// 950.130 us; speedup vs baseline: 1.6265x; 1.6265x over previous
//
#include <hip/hip_runtime.h>
#include <math.h>

// Performer encoder on MI355X: B=4, S=4096, D=256, H=4, DH=64, L=4, M=266.
// bf16 MFMA everywhere; fp32 residual stream / LN stats / softmax logic.
// Round 8: r6 structure restored (r7's 16-row tiling regressed 3.5x — weight re-staging
// scales with block count); fullrow GEMM now 512 threads / 8 waves per 64-row block
// (same per-block traffic as r6, 2x the waves to hide the load->barrier chain).

#define WS_ALIGN(x) (((x) + 255) & ~(size_t)255)

#define DN 0.35355339059327373f      // 64^-0.25
#define DIAGC 0.0625f                 // 0.5 * 64^-0.5
#define RATIO 0.06131393394849658f    // 266^-0.5
#define FEPS 1e-4f

typedef __attribute__((__ext_vector_type__(8))) __bf16 bf16x8;
typedef __attribute__((__ext_vector_type__(4))) float f32x4;

__device__ __forceinline__ float wredsum(float v) {
    v += __shfl_xor(v, 32); v += __shfl_xor(v, 16); v += __shfl_xor(v, 8);
    v += __shfl_xor(v, 4);  v += __shfl_xor(v, 2);  v += __shfl_xor(v, 1);
    return v;
}
__device__ __forceinline__ float wredmax(float v) {
    v = fmaxf(v, __shfl_xor(v, 32)); v = fmaxf(v, __shfl_xor(v, 16));
    v = fmaxf(v, __shfl_xor(v, 8));  v = fmaxf(v, __shfl_xor(v, 4));
    v = fmaxf(v, __shfl_xor(v, 2));  v = fmaxf(v, __shfl_xor(v, 1));
    return v;
}

__device__ __forceinline__ unsigned short f2bf(float f) {
    unsigned u = __builtin_bit_cast(unsigned, f);
    return (unsigned short)((u + 0x7fffu + ((u >> 16) & 1u)) >> 16);
}
__device__ __forceinline__ float blo(unsigned x) { return __builtin_bit_cast(float, x << 16); }
__device__ __forceinline__ float bhi(unsigned x) { return __builtin_bit_cast(float, x & 0xffff0000u); }
__device__ __forceinline__ float sumsq8(uint4 u) {
    float s = 0.f;
    s += blo(u.x)*blo(u.x) + bhi(u.x)*bhi(u.x);
    s += blo(u.y)*blo(u.y) + bhi(u.y)*bhi(u.y);
    s += blo(u.z)*blo(u.z) + bhi(u.z)*bhi(u.z);
    s += blo(u.w)*blo(u.w) + bhi(u.w)*bhi(u.w);
    return s;
}

// ---------------- LayerNorm (fp32 in, fp32 or bf16 out) ----------------
template <bool OBF>
__global__ __launch_bounds__(256) void add_ln_kernel(
    const float* __restrict__ in, const float* __restrict__ pos,
    const float* __restrict__ g, const float* __restrict__ bta,
    float* __restrict__ outf, unsigned short* __restrict__ outb)
{
    int row = blockIdx.x, t = threadIdx.x;
    __shared__ float sred[4];
    float v = in[(size_t)row * 256 + t];
    if (pos) v += pos[(size_t)(row & 4095) * 256 + t];
    float s = wredsum(v);
    if ((t & 63) == 0) sred[t >> 6] = s;
    __syncthreads();
    float mean = (sred[0] + sred[1] + sred[2] + sred[3]) * (1.0f / 256.0f);
    float d = v - mean;
    __syncthreads();
    float sq = wredsum(d * d);
    if ((t & 63) == 0) sred[t >> 6] = sq;
    __syncthreads();
    float var = (sred[0] + sred[1] + sred[2] + sred[3]) * (1.0f / 256.0f);
    float y = d * rsqrtf(var + 1e-12f) * g[t] + bta[t];
    if (OBF) outb[(size_t)row * 256 + t] = f2bf(y);
    else     outf[(size_t)row * 256 + t] = y;
}

// ---------------- weight cast/transpose: fp32 [R][C] -> bf16 [C][R] ----------------
__global__ __launch_bounds__(256) void cast_transpose_kernel(
    const float* __restrict__ in, unsigned short* __restrict__ out, int R, int C)
{
    __shared__ float tile[32][33];
    size_t zo = (size_t)blockIdx.z * R * C;
    int c0 = blockIdx.x * 32, r0 = blockIdx.y * 32;
    int t = threadIdx.x, tc = t & 31, tr = t >> 5;
#pragma unroll
    for (int j = 0; j < 4; j++)
        tile[tr + j * 8][tc] = in[zo + (size_t)(r0 + tr + j * 8) * C + c0 + tc];
    __syncthreads();
#pragma unroll
    for (int j = 0; j < 4; j++) {
        int cc = tr + j * 8, rr = tc;
        out[zo + (size_t)(c0 + cc) * R + r0 + rr] = f2bf(tile[rr][cc]);
    }
}

// fp32 -> bf16 elementwise (n4 = count/4)
__global__ __launch_bounds__(256) void cast_row_kernel(
    const float4* __restrict__ in, ushort4* __restrict__ out, int n4)
{
    int i = blockIdx.x * 256 + threadIdx.x;
    if (i >= n4) return;
    float4 v = in[i];
    ushort4 o; o.x = f2bf(v.x); o.y = f2bf(v.y); o.z = f2bf(v.z); o.w = f2bf(v.w);
    out[i] = o;
}

// ---------------- fused QKV GEMM (N=768 over q|k|v), K=256 ----------------
__global__ __launch_bounds__(256) void qkv_kernel(
    const unsigned short* __restrict__ A,
    const unsigned short* __restrict__ Wqt, const unsigned short* __restrict__ Wkt,
    const unsigned short* __restrict__ Wvt,
    const float* __restrict__ bq, const float* __restrict__ bk, const float* __restrict__ bv,
    unsigned short* __restrict__ qbf, unsigned short* __restrict__ kbf,
    unsigned short* __restrict__ vT)
{
    __shared__ uint4 As[128][5];
    __shared__ uint4 Bs[64][5];
    const int K = 256;
    int t = threadIdx.x;
    int bm = blockIdx.y * 128, bn = blockIdx.x * 64;
    int grp = bn >> 8, lbn = bn & 255;
    const unsigned short* Bt = (grp == 0) ? Wqt : (grp == 1) ? Wkt : Wvt;
    const float* bias = (grp == 0) ? bq : (grp == 1) ? bk : bv;
    int w = t >> 6, l = t & 63, lm16 = l & 15, quad = l >> 4;
    int ar = t >> 1, ak = (t & 1) * 16;
    int br = t >> 2, bk2 = (t & 3) * 8;
    const unsigned short* Ab = A + (size_t)(bm + ar) * K + ak;
    const unsigned short* Bb = Bt + (size_t)(lbn + br) * K + bk2;
    f32x4 acc[2][4] = {};
    for (int k0 = 0; k0 < K; k0 += 32) {
        uint4 a0 = *(const uint4*)(Ab + k0);
        uint4 a1 = *(const uint4*)(Ab + k0 + 8);
        uint4 b0 = *(const uint4*)(Bb + k0);
        __syncthreads();
        As[ar][(ak >> 3)] = a0; As[ar][(ak >> 3) + 1] = a1;
        Bs[br][bk2 >> 3] = b0;
        __syncthreads();
        bf16x8 af[2], bfr[4];
        af[0] = *(const bf16x8*)&As[w * 32 + lm16][quad];
        af[1] = *(const bf16x8*)&As[w * 32 + 16 + lm16][quad];
#pragma unroll
        for (int j = 0; j < 4; j++) bfr[j] = *(const bf16x8*)&Bs[j * 16 + lm16][quad];
#pragma unroll
        for (int i = 0; i < 2; i++)
#pragma unroll
            for (int j = 0; j < 4; j++)
                acc[i][j] = __builtin_amdgcn_mfma_f32_16x16x32_bf16(af[i], bfr[j], acc[i][j], 0, 0, 0);
    }
#pragma unroll
    for (int i = 0; i < 2; i++)
#pragma unroll
        for (int j = 0; j < 4; j++) {
            int lcol = lbn + j * 16 + lm16;
            float bs = bias[lcol];
            int h = lcol >> 6, e = lcol & 63;
#pragma unroll
            for (int r = 0; r < 4; r++) {
                int row = bm + w * 32 + i * 16 + quad * 4 + r;
                int b = row >> 12, s = row & 4095;
                float v = acc[i][j][r] + bs;
                if (grp == 0)
                    qbf[((size_t)((b << 2) + h) * 4096 + s) * 64 + e] = f2bf(v);
                else if (grp == 1)
                    kbf[((size_t)((b << 2) + h) * 4096 + s) * 64 + e] = f2bf(v);
                else
                    vT[((size_t)((b << 2) + h) * 64 + e) * 4096 + s] = f2bf(v);
            }
        }
}

// ---------------- FFN1 GEMM: gelu(tanh) epilogue, bf16 out ----------------
__global__ __launch_bounds__(256) void ffn1_kernel(
    const unsigned short* __restrict__ A, const unsigned short* __restrict__ Bt,
    const float* __restrict__ bias, unsigned short* __restrict__ Cb, int N, int K)
{
    __shared__ uint4 As[128][5];
    __shared__ uint4 Bs[64][5];
    int t = threadIdx.x;
    int bm = blockIdx.y * 128, bn = blockIdx.x * 64;
    int w = t >> 6, l = t & 63, lm16 = l & 15, quad = l >> 4;
    int ar = t >> 1, ak = (t & 1) * 16;
    int br = t >> 2, bk = (t & 3) * 8;
    const unsigned short* Ab = A + (size_t)(bm + ar) * K + ak;
    const unsigned short* Bb = Bt + (size_t)(bn + br) * K + bk;
    f32x4 acc[2][4] = {};
    for (int k0 = 0; k0 < K; k0 += 32) {
        uint4 a0 = *(const uint4*)(Ab + k0);
        uint4 a1 = *(const uint4*)(Ab + k0 + 8);
        uint4 b0 = *(const uint4*)(Bb + k0);
        __syncthreads();
        As[ar][(ak >> 3)] = a0; As[ar][(ak >> 3) + 1] = a1;
        Bs[br][bk >> 3] = b0;
        __syncthreads();
        bf16x8 af[2], bfr[4];
        af[0] = *(const bf16x8*)&As[w * 32 + lm16][quad];
        af[1] = *(const bf16x8*)&As[w * 32 + 16 + lm16][quad];
#pragma unroll
        for (int j = 0; j < 4; j++) bfr[j] = *(const bf16x8*)&Bs[j * 16 + lm16][quad];
#pragma unroll
        for (int i = 0; i < 2; i++)
#pragma unroll
            for (int j = 0; j < 4; j++)
                acc[i][j] = __builtin_amdgcn_mfma_f32_16x16x32_bf16(af[i], bfr[j], acc[i][j], 0, 0, 0);
    }
#pragma unroll
    for (int i = 0; i < 2; i++)
#pragma unroll
        for (int j = 0; j < 4; j++) {
            int col = bn + j * 16 + lm16;
            float bsv = bias[col];
#pragma unroll
            for (int r = 0; r < 4; r++) {
                int row = bm + w * 32 + i * 16 + quad * 4 + r;
                float v = acc[i][j][r] + bsv;
                float inner = 0.7978845608028654f * (v + 0.044715f * v * v * v);
                float gl = 0.5f * v * (1.0f + tanhf(inner));
                Cb[(size_t)row * N + col] = f2bf(gl);
            }
        }
}

// ---------------- fused full-row GEMM: 64 rows x N=256 per block, 512 threads ----------
// 8 waves; wave w computes all 64 rows x cols [w*32, w*32+32). Grid = M/64 = 256.
// EPI 0: +bias +resid(xio); write xio fp32; LayerNorm -> outb bf16
// EPI 1: +bias +resid(xio); write xio fp32; plain bf16 cast -> outb
// EPI 2: pooling: alpha[row] = exp(sum_col tanh(v+bias)*p2w + p2b) * mask[row]
template <int EPI>
__global__ __launch_bounds__(512) void gemm_fullrow_kernel(
    const unsigned short* __restrict__ A, const unsigned short* __restrict__ Bt,
    const float* __restrict__ bias, float* __restrict__ xio,
    const float* __restrict__ lng, const float* __restrict__ lnb,
    unsigned short* __restrict__ outb,
    const float* __restrict__ p2w, const float* __restrict__ p2b,
    const float* __restrict__ mask, float* __restrict__ alphab, int K)
{
    __shared__ uint4 As4[64][5];
    __shared__ uint4 Bs4[256][5];
    __shared__ float red[8][64];
    int t = threadIdx.x;
    int bm = blockIdx.x * 64;
    int w = t >> 6, l = t & 63, lm16 = l & 15, quad = l >> 4;
    int br = t >> 2, bj = t & 3;
    f32x4 acc[4][2] = {};
    for (int k0 = 0; k0 < K; k0 += 32) {
        uint4 a = {0, 0, 0, 0};
        if (t < 256) a = *(const uint4*)(A + (size_t)(bm + (t >> 2)) * K + k0 + (t & 3) * 8);
        uint4 b0 = *(const uint4*)(Bt + (size_t)br * K + k0 + bj * 8);
        uint4 b1 = *(const uint4*)(Bt + (size_t)(br + 128) * K + k0 + bj * 8);
        __syncthreads();
        if (t < 256) As4[t >> 2][t & 3] = a;
        Bs4[br][bj] = b0;
        Bs4[br + 128][bj] = b1;
        __syncthreads();
        bf16x8 af[4], bfv[2];
#pragma unroll
        for (int i = 0; i < 4; i++) af[i] = *(const bf16x8*)&As4[i * 16 + lm16][quad];
#pragma unroll
        for (int j = 0; j < 2; j++) bfv[j] = *(const bf16x8*)&Bs4[w * 32 + j * 16 + lm16][quad];
#pragma unroll
        for (int i = 0; i < 4; i++)
#pragma unroll
            for (int j = 0; j < 2; j++)
                acc[i][j] = __builtin_amdgcn_mfma_f32_16x16x32_bf16(af[i], bfv[j], acc[i][j], 0, 0, 0);
    }
    int colbase = w * 32;
    if (EPI == 2) {
        float rs[4][4] = {};
#pragma unroll
        for (int j = 0; j < 2; j++) {
            int col = colbase + j * 16 + lm16;
            float bs = bias[col], pw = p2w[col];
#pragma unroll
            for (int i = 0; i < 4; i++)
#pragma unroll
                for (int r = 0; r < 4; r++)
                    rs[i][r] += tanhf(acc[i][j][r] + bs) * pw;
        }
#pragma unroll
        for (int m2 = 1; m2 <= 8; m2 <<= 1)
#pragma unroll
            for (int i = 0; i < 4; i++)
#pragma unroll
                for (int r = 0; r < 4; r++) rs[i][r] += __shfl_xor(rs[i][r], m2);
        __syncthreads();
        if (lm16 == 0) {
#pragma unroll
            for (int i = 0; i < 4; i++)
#pragma unroll
                for (int r = 0; r < 4; r++) red[w][i * 16 + quad * 4 + r] = rs[i][r];
        }
        __syncthreads();
        if (t < 64) {
            float sc = p2b[0];
#pragma unroll
            for (int ww = 0; ww < 8; ww++) sc += red[ww][t];
            int row = bm + t;
            alphab[row] = expf(sc) * mask[row];
        }
        return;
    }
    float rs[4][4] = {};
#pragma unroll
    for (int j = 0; j < 2; j++) {
        int col = colbase + j * 16 + lm16;
        float bs = bias[col];
#pragma unroll
        for (int i = 0; i < 4; i++)
#pragma unroll
            for (int r = 0; r < 4; r++) {
                int row = bm + i * 16 + quad * 4 + r;
                float v = acc[i][j][r] + bs + xio[(size_t)row * 256 + col];
                acc[i][j][r] = v;
                rs[i][r] += v;
            }
    }
    float mean[4][4], rstd[4][4];
    if (EPI == 0) {
#pragma unroll
        for (int m2 = 1; m2 <= 8; m2 <<= 1)
#pragma unroll
            for (int i = 0; i < 4; i++)
#pragma unroll
                for (int r = 0; r < 4; r++) rs[i][r] += __shfl_xor(rs[i][r], m2);
        __syncthreads();
        if (lm16 == 0) {
#pragma unroll
            for (int i = 0; i < 4; i++)
#pragma unroll
                for (int r = 0; r < 4; r++) red[w][i * 16 + quad * 4 + r] = rs[i][r];
        }
        __syncthreads();
        float vs[4][4] = {};
#pragma unroll
        for (int i = 0; i < 4; i++)
#pragma unroll
            for (int r = 0; r < 4; r++) {
                int rr = i * 16 + quad * 4 + r;
                float s = 0.f;
#pragma unroll
                for (int ww = 0; ww < 8; ww++) s += red[ww][rr];
                mean[i][r] = s * (1.0f / 256.0f);
            }
#pragma unroll
        for (int j = 0; j < 2; j++)
#pragma unroll
            for (int i = 0; i < 4; i++)
#pragma unroll
                for (int r = 0; r < 4; r++) {
                    float d = acc[i][j][r] - mean[i][r];
                    vs[i][r] += d * d;
                }
#pragma unroll
        for (int m2 = 1; m2 <= 8; m2 <<= 1)
#pragma unroll
            for (int i = 0; i < 4; i++)
#pragma unroll
                for (int r = 0; r < 4; r++) vs[i][r] += __shfl_xor(vs[i][r], m2);
        __syncthreads();
        if (lm16 == 0) {
#pragma unroll
            for (int i = 0; i < 4; i++)
#pragma unroll
                for (int r = 0; r < 4; r++) red[w][i * 16 + quad * 4 + r] = vs[i][r];
        }
        __syncthreads();
#pragma unroll
        for (int i = 0; i < 4; i++)
#pragma unroll
            for (int r = 0; r < 4; r++) {
                int rr = i * 16 + quad * 4 + r;
                float s = 0.f;
#pragma unroll
                for (int ww = 0; ww < 8; ww++) s += red[ww][rr];
                rstd[i][r] = rsqrtf(s * (1.0f / 256.0f) + 1e-12f);
            }
    }
#pragma unroll
    for (int j = 0; j < 2; j++) {
        int col = colbase + j * 16 + lm16;
        float g  = (EPI == 0) ? lng[col] : 0.f;
        float bb = (EPI == 0) ? lnb[col] : 0.f;
#pragma unroll
        for (int i = 0; i < 4; i++)
#pragma unroll
            for (int r = 0; r < 4; r++) {
                int row = bm + i * 16 + quad * 4 + r;
                float v = acc[i][j][r];
                xio[(size_t)row * 256 + col] = v;
                float y = (EPI == 0) ? ((v - mean[i][r]) * rstd[i][r] * g + bb) : v;
                outb[(size_t)row * 256 + col] = f2bf(y);
            }
    }
}

// ---------------- phi row kernel: 64 s x 272 m per block ----------------
// MODE 0 (q): dash -> row max -> exp -> qp bf16 [bh][s][272]; denom = qp.ksum
// MODE 1 (k): dash -> block max -> pmax[bh*64 + blk]
template <int MODE>
__global__ __launch_bounds__(256) void phi_row_kernel(
    const unsigned short* __restrict__ xbf, const unsigned short* __restrict__ projbf,
    const float* __restrict__ ksum, unsigned short* __restrict__ qp,
    float* __restrict__ denomb, float* __restrict__ pmax)
{
    __shared__ uint4 As[64][9];
    __shared__ uint4 Bs[272][9];
    __shared__ float diag_s[64];
    __shared__ float ks_s[272];
    __shared__ float sred[4];
    int t = threadIdx.x;
    int s0 = blockIdx.x * 64;
    int bh = blockIdx.y;
    {
        int arow = t >> 2, akoff = (t & 3) * 16;
        const uint4* ga = (const uint4*)(xbf + ((size_t)bh * 4096 + s0 + arow) * 64 + akoff);
        uint4 u0 = ga[0], u1 = ga[1];
        As[arow][(akoff >> 3)] = u0; As[arow][(akoff >> 3) + 1] = u1;
        float ss = sumsq8(u0) + sumsq8(u1);
        ss += __shfl_xor(ss, 1); ss += __shfl_xor(ss, 2);
        if ((t & 3) == 0) diag_s[arow] = DIAGC * ss;
        uint4 zero = {0, 0, 0, 0};
        for (int row = t; row < 272; row += 256) {
            const uint4* gp = (const uint4*)(projbf + (size_t)row * 64);
            bool bv = row < 266;
#pragma unroll
            for (int i2 = 0; i2 < 8; i2++) Bs[row][i2] = bv ? gp[i2] : zero;
        }
        if (MODE == 0) {
            ks_s[t] = ksum[bh * 272 + t];
            if (t < 16) ks_s[256 + t] = ksum[bh * 272 + 256 + t];
        }
    }
    __syncthreads();
    int w = t >> 6, l = t & 63, lm16 = l & 15, quad = l >> 4;
    f32x4 acc[17] = {};
#pragma unroll
    for (int ks = 0; ks < 2; ks++) {
        bf16x8 af = *(const bf16x8*)&As[w * 16 + lm16][ks * 4 + quad];
#pragma unroll
        for (int j = 0; j < 17; j++) {
            bf16x8 bfv = *(const bf16x8*)&Bs[j * 16 + lm16][ks * 4 + quad];
            acc[j] = __builtin_amdgcn_mfma_f32_16x16x32_bf16(af, bfv, acc[j], 0, 0, 0);
        }
    }
    int rloc = w * 16 + quad * 4;
    float dg[4];
#pragma unroll
    for (int r = 0; r < 4; r++) dg[r] = diag_s[rloc + r];
    if (MODE == 1) {
        float kmax = -1e30f;
#pragma unroll
        for (int j = 0; j < 17; j++) {
            int m = j * 16 + lm16;
            bool valid = m < 266;
#pragma unroll
            for (int r = 0; r < 4; r++)
                if (valid) kmax = fmaxf(kmax, acc[j][r] * DN - dg[r]);
        }
        kmax = wredmax(kmax);
        if (l == 0) sred[w] = kmax;
        __syncthreads();
        if (t == 0)
            pmax[(size_t)bh * 64 + blockIdx.x] =
                fmaxf(fmaxf(sred[0], sred[1]), fmaxf(sred[2], sred[3]));
        return;
    }
    float vmax[4] = {-1e30f, -1e30f, -1e30f, -1e30f};
#pragma unroll
    for (int j = 0; j < 17; j++) {
        int m = j * 16 + lm16;
        bool valid = m < 266;
#pragma unroll
        for (int r = 0; r < 4; r++) {
            float v = acc[j][r] * DN - dg[r];
            acc[j][r] = v;
            if (valid) vmax[r] = fmaxf(vmax[r], v);
        }
    }
#pragma unroll
    for (int m2 = 1; m2 <= 8; m2 <<= 1)
#pragma unroll
        for (int r = 0; r < 4; r++) vmax[r] = fmaxf(vmax[r], __shfl_xor(vmax[r], m2));
    float den[4] = {0.f, 0.f, 0.f, 0.f};
#pragma unroll
    for (int j = 0; j < 17; j++) {
        int m = j * 16 + lm16;
        bool valid = m < 266;
#pragma unroll
        for (int r = 0; r < 4; r++) {
            float e = valid ? RATIO * (expf(acc[j][r] - vmax[r]) + FEPS) : 0.f;
            qp[((size_t)bh * 4096 + s0 + rloc + r) * 272 + m] = f2bf(e);
            den[r] += e * ks_s[m];
        }
    }
#pragma unroll
    for (int m2 = 1; m2 <= 8; m2 <<= 1)
#pragma unroll
        for (int r = 0; r < 4; r++) den[r] += __shfl_xor(den[r], m2);
    if (lm16 == 0) {
#pragma unroll
        for (int r = 0; r < 4; r++)
            denomb[(size_t)bh * 4096 + s0 + rloc + r] = den[r];
    }
}

__global__ __launch_bounds__(256) void reduce_max_kernel(
    const float* __restrict__ pmax, float* __restrict__ stab, int n)
{
    __shared__ float sred[4];
    int t = threadIdx.x;
    float m = -1e30f;
    for (int i = t; i < n; i += 256) m = fmaxf(m, pmax[i]);
    m = wredmax(m);
    if ((t & 63) == 0) sred[t >> 6] = m;
    __syncthreads();
    if (t == 0) stab[0] = fmaxf(fmaxf(sred[0], sred[1]), fmaxf(sred[2], sred[3]));
}

// ---------------- fused ctx: dash -> exp -> (LDS transform) -> ctx MFMA + ksum ----------------
__global__ __launch_bounds__(256) void ctx_fused_kernel(
    const unsigned short* __restrict__ kbf, const unsigned short* __restrict__ vT,
    const unsigned short* __restrict__ projbf, const float* __restrict__ stab,
    float* __restrict__ ksum, float* __restrict__ ctxT)
{
    __shared__ uint4 Ap[64][9];               // proj tile [m_loc][k]
    __shared__ uint4 Ks[64][9];               // k chunk   [s_loc][k]
    __shared__ uint4 Vs[64][9];               // v chunk   [e][s_loc]
    __shared__ unsigned short kp_s[64][72];   // kp tile   [m_loc][s_loc]
    __shared__ float diag_s[64];
    int t = threadIdx.x;
    int m0 = blockIdx.x * 64;
    int bh = blockIdx.y;
    int sb = blockIdx.z * 512;
    int w = t >> 6, l = t & 63, lm16 = l & 15, quad = l >> 4;
    {
        int row = t >> 2, koff = (t & 3) * 16;
        uint4 zero = {0, 0, 0, 0};
        bool bv = (m0 + row) < 266;
        const uint4* gp = (const uint4*)(projbf + (size_t)(m0 + row) * 64 + koff);
        Ap[row][(koff >> 3)] = bv ? gp[0] : zero;
        Ap[row][(koff >> 3) + 1] = bv ? gp[1] : zero;
    }
    float st = stab[0];
    f32x4 accc[4] = {};
    float ksacc[4] = {0.f, 0.f, 0.f, 0.f};
    int srow = t >> 2, skoff = (t & 3) * 16;
    for (int kc = 0; kc < 8; kc++) {
        int sc = sb + kc * 64;
        const uint4* gk = (const uint4*)(kbf + ((size_t)bh * 4096 + sc + srow) * 64 + skoff);
        uint4 k0 = gk[0], k1 = gk[1];
        const uint4* gv = (const uint4*)(vT + ((size_t)bh * 64 + srow) * 4096 + sc + skoff);
        uint4 v0 = gv[0], v1 = gv[1];
        __syncthreads();
        Ks[srow][(skoff >> 3)] = k0; Ks[srow][(skoff >> 3) + 1] = k1;
        Vs[srow][(skoff >> 3)] = v0; Vs[srow][(skoff >> 3) + 1] = v1;
        float ss = sumsq8(k0) + sumsq8(k1);
        ss += __shfl_xor(ss, 1); ss += __shfl_xor(ss, 2);
        if ((t & 3) == 0) diag_s[srow] = DIAGC * ss;
        __syncthreads();
        f32x4 accd[4] = {};
#pragma unroll
        for (int ks = 0; ks < 2; ks++) {
            bf16x8 af = *(const bf16x8*)&Ap[w * 16 + lm16][ks * 4 + quad];
#pragma unroll
            for (int j = 0; j < 4; j++) {
                bf16x8 bfv = *(const bf16x8*)&Ks[j * 16 + lm16][ks * 4 + quad];
                accd[j] = __builtin_amdgcn_mfma_f32_16x16x32_bf16(af, bfv, accd[j], 0, 0, 0);
            }
        }
        int mbase = m0 + w * 16 + quad * 4;
#pragma unroll
        for (int j = 0; j < 4; j++) {
            int s_loc = j * 16 + lm16;
            float dgv = diag_s[s_loc];
#pragma unroll
            for (int r = 0; r < 4; r++) {
                float v = accd[j][r] * DN - dgv;
                float e = (mbase + r < 266) ? RATIO * (expf(v - st) + FEPS) : 0.f;
                kp_s[w * 16 + quad * 4 + r][s_loc] = f2bf(e);
                ksacc[r] += e;
            }
        }
        __syncthreads();
#pragma unroll
        for (int ks = 0; ks < 2; ks++) {
            bf16x8 af = *(const bf16x8*)&Vs[w * 16 + lm16][ks * 4 + quad];
#pragma unroll
            for (int jt = 0; jt < 4; jt++) {
                bf16x8 bfv = *(const bf16x8*)&kp_s[jt * 16 + lm16][ks * 32 + quad * 8];
                accc[jt] = __builtin_amdgcn_mfma_f32_16x16x32_bf16(af, bfv, accc[jt], 0, 0, 0);
            }
        }
    }
#pragma unroll
    for (int r = 0; r < 4; r++) {
        float v = ksacc[r];
        v += __shfl_xor(v, 1); v += __shfl_xor(v, 2);
        v += __shfl_xor(v, 4); v += __shfl_xor(v, 8);
        if (lm16 == 0) {
            int m = m0 + w * 16 + quad * 4 + r;
            if (m < 272) atomicAdd(&ksum[bh * 272 + m], v);
        }
    }
#pragma unroll
    for (int jt = 0; jt < 4; jt++) {
        int m = m0 + jt * 16 + lm16;
        if (m >= 272) continue;
#pragma unroll
        for (int r = 0; r < 4; r++) {
            int e = w * 16 + quad * 4 + r;
            atomicAdd(&ctxT[((size_t)bh * 64 + e) * 272 + m], accc[jt][r]);
        }
    }
}

// ---------------- attn MFMA: out = (qp @ ctxT^T)/denom -> abf [b][s][h*64+e] ----------------
__global__ __launch_bounds__(256) void attn_mfma_kernel(
    const unsigned short* __restrict__ qp, const unsigned short* __restrict__ ctxTbf,
    const float* __restrict__ denomb, unsigned short* __restrict__ abf)
{
    __shared__ uint4 As[128][5];
    __shared__ uint4 Bs[64][5];
    int t = threadIdx.x;
    int s0 = blockIdx.x * 128;
    int bh = blockIdx.y; int b = bh >> 2, h = bh & 3;
    int w = t >> 6, l = t & 63, lm16 = l & 15, quad = l >> 4;
    int ar = t >> 1, ak = (t & 1) * 16;
    int br = t >> 2, bk = (t & 3) * 8;
    const unsigned short* Ab = qp + ((size_t)bh * 4096 + s0 + ar) * 272 + ak;
    const unsigned short* Bb = ctxTbf + ((size_t)bh * 64 + br) * 272 + bk;
    uint4 zero = {0, 0, 0, 0};
    f32x4 acc[2][4] = {};
    for (int k0 = 0; k0 < 272; k0 += 32) {
        uint4 a0 = (k0 + ak < 272)     ? *(const uint4*)(Ab + k0)     : zero;
        uint4 a1 = (k0 + ak + 8 < 272) ? *(const uint4*)(Ab + k0 + 8) : zero;
        uint4 b0 = (k0 + bk < 272)     ? *(const uint4*)(Bb + k0)     : zero;
        __syncthreads();
        As[ar][(ak >> 3)] = a0; As[ar][(ak >> 3) + 1] = a1;
        Bs[br][bk >> 3] = b0;
        __syncthreads();
        bf16x8 af[2], bfr[4];
        af[0] = *(const bf16x8*)&As[w * 32 + lm16][quad];
        af[1] = *(const bf16x8*)&As[w * 32 + 16 + lm16][quad];
#pragma unroll
        for (int j = 0; j < 4; j++) bfr[j] = *(const bf16x8*)&Bs[j * 16 + lm16][quad];
#pragma unroll
        for (int i = 0; i < 2; i++)
#pragma unroll
            for (int j = 0; j < 4; j++)
                acc[i][j] = __builtin_amdgcn_mfma_f32_16x16x32_bf16(af[i], bfr[j], acc[i][j], 0, 0, 0);
    }
#pragma unroll
    for (int i = 0; i < 2; i++)
#pragma unroll
        for (int j = 0; j < 4; j++)
#pragma unroll
            for (int r = 0; r < 4; r++) {
                int s = s0 + w * 32 + i * 16 + quad * 4 + r;
                float v = acc[i][j][r] / denomb[(size_t)bh * 4096 + s];
                int e = j * 16 + lm16;
                abf[((size_t)(b * 4096 + s)) * 256 + h * 64 + e] = f2bf(v);
            }
}

// ---------------- pooling tail ----------------
__global__ __launch_bounds__(256) void pool_denom_kernel(
    const float* __restrict__ alpha, float* __restrict__ denomb)
{
    __shared__ float sred[4];
    int b = blockIdx.x, t = threadIdx.x;
    float p = 0.f;
    for (int s = t; s < 4096; s += 256) p += alpha[b * 4096 + s];
    p = wredsum(p);
    if ((t & 63) == 0) sred[t >> 6] = p;
    __syncthreads();
    if (t == 0) denomb[b] = sred[0] + sred[1] + sred[2] + sred[3] + 1e-8f;
}

__global__ __launch_bounds__(256) void pool_out_kernel(
    const float* __restrict__ x, const float* __restrict__ alpha,
    const float* __restrict__ denomb, float* __restrict__ out)
{
    int b = blockIdx.x, chunk = blockIdx.y, t = threadIdx.x;
    float inv = 1.0f / denomb[b];
    float acc = 0.f;
    int s0 = chunk * 128;
    for (int s = s0; s < s0 + 128; s++)
        acc += x[((size_t)(b << 12) + s) * 256 + t] * alpha[(b << 12) + s];
    atomicAdd(&out[b * 256 + t], acc * inv);
}

extern "C" void kernel_launch(void* const* d_in, const int* in_sizes, int n_in,
                              void* d_out, int out_size, void* d_ws, size_t ws_size,
                              hipStream_t stream)
{
    const float* input_embs = (const float*)d_in[0];
    const float* mask  = (const float*)d_in[1];
    const float* pos   = (const float*)d_in[2];
    const float* ln_g  = (const float*)d_in[3];
    const float* ln_b  = (const float*)d_in[4];
    const float* proj  = (const float*)d_in[5];
    const float* Wq = (const float*)d_in[6];  const float* bq = (const float*)d_in[7];
    const float* Wk = (const float*)d_in[8];  const float* bk = (const float*)d_in[9];
    const float* Wv = (const float*)d_in[10]; const float* bv = (const float*)d_in[11];
    const float* Wo = (const float*)d_in[12]; const float* bo = (const float*)d_in[13];
    const float* ln1g = (const float*)d_in[14]; const float* ln1b = (const float*)d_in[15];
    const float* W1 = (const float*)d_in[16]; const float* b1 = (const float*)d_in[17];
    const float* W2 = (const float*)d_in[18]; const float* b2 = (const float*)d_in[19];
    const float* ln2g = (const float*)d_in[20]; const float* ln2b = (const float*)d_in[21];
    const float* p1w = (const float*)d_in[22]; const float* p1b = (const float*)d_in[23];
    const float* p2w = (const float*)d_in[24]; const float* p2b = (const float*)d_in[25];
    float* out = (float*)d_out;
    char* ws = (char*)d_ws;

    size_t off = 0;
    auto alloc = [&](size_t bytes) { size_t o = off; off += WS_ALIGN(bytes); return o; };
    float* xbuf = (float*)(ws + alloc(16384ull * 256 * 4));
    unsigned short* hbf = (unsigned short*)(ws + alloc(16384ull * 256 * 2));   // ln-out / attn-out
    unsigned short* qbf = (unsigned short*)(ws + alloc(16384ull * 256 * 2));
    unsigned short* kbf = (unsigned short*)(ws + alloc(16384ull * 256 * 2));
    unsigned short* vT  = (unsigned short*)(ws + alloc(16384ull * 256 * 2));
    unsigned short* qp  = (unsigned short*)(ws + alloc(16ull * 4096 * 272 * 2)); // alias: FFN mid
    size_t ksum_off = alloc(16ull * 272 * 4);
    float* ksum = (float*)(ws + ksum_off);
    float* ctxT = (float*)(ws + alloc(16ull * 64 * 272 * 4));      // adjacent to ksum (one memset)
    size_t zero_bytes = WS_ALIGN(16ull * 272 * 4) + WS_ALIGN(16ull * 64 * 272 * 4);
    unsigned short* ctxTbf = (unsigned short*)(ws + alloc(16ull * 64 * 272 * 2));
    float* denomb = (float*)(ws + alloc(65536ull * 4));
    float* pmaxb = (float*)(ws + alloc(1024ull * 4));
    float* stabb = (float*)(ws + alloc(256));
    float* alphab = (float*)(ws + alloc(16384ull * 4));
    float* pdenom = (float*)(ws + alloc(256));
    unsigned short* Wqt = (unsigned short*)(ws + alloc(4ull * 65536 * 2));
    unsigned short* Wkt = (unsigned short*)(ws + alloc(4ull * 65536 * 2));
    unsigned short* Wvt = (unsigned short*)(ws + alloc(4ull * 65536 * 2));
    unsigned short* Wot = (unsigned short*)(ws + alloc(4ull * 65536 * 2));
    unsigned short* W1t = (unsigned short*)(ws + alloc(4ull * 262144 * 2));
    unsigned short* W2t = (unsigned short*)(ws + alloc(4ull * 262144 * 2));
    unsigned short* projbf = (unsigned short*)(ws + alloc(4ull * 17024 * 2));
    unsigned short* p1t = (unsigned short*)(ws + alloc(65536ull * 2));
    unsigned short* midbf = qp;   // FFN intermediate aliases qp (disjoint lifetimes)
    unsigned short* abf = hbf;
    // total ~95 MB (< 256 MiB)

    // ---- weight casts (all layers up front) ----
    cast_transpose_kernel<<<dim3(8, 8, 4), 256, 0, stream>>>(Wq, Wqt, 256, 256);
    cast_transpose_kernel<<<dim3(8, 8, 4), 256, 0, stream>>>(Wk, Wkt, 256, 256);
    cast_transpose_kernel<<<dim3(8, 8, 4), 256, 0, stream>>>(Wv, Wvt, 256, 256);
    cast_transpose_kernel<<<dim3(8, 8, 4), 256, 0, stream>>>(Wo, Wot, 256, 256);
    cast_transpose_kernel<<<dim3(32, 8, 4), 256, 0, stream>>>(W1, W1t, 256, 1024);
    cast_transpose_kernel<<<dim3(8, 32, 4), 256, 0, stream>>>(W2, W2t, 1024, 256);
    cast_transpose_kernel<<<dim3(8, 8, 1), 256, 0, stream>>>(p1w, p1t, 256, 256);
    cast_row_kernel<<<67, 256, 0, stream>>>((const float4*)proj, (ushort4*)projbf, 17024);

    // ---- x = LN(input + pos); hbf = LN1_0(x) ----
    add_ln_kernel<false><<<16384, 256, 0, stream>>>(input_embs, pos, ln_g, ln_b, xbuf, nullptr);
    add_ln_kernel<true><<<16384, 256, 0, stream>>>(xbuf, nullptr, ln1g, ln1b, nullptr, hbf);

    for (int i = 0; i < 4; i++) {
        const unsigned short* pj = projbf + (size_t)i * 17024;
        // QKV fused
        qkv_kernel<<<dim3(12, 128), 256, 0, stream>>>(hbf,
            Wqt + (size_t)i * 65536, Wkt + (size_t)i * 65536, Wvt + (size_t)i * 65536,
            bq + i * 256, bk + i * 256, bv + i * 256, qbf, kbf, vT);
        // k stabilizer: dash max (row tiling) -> global reduce
        phi_row_kernel<1><<<dim3(64, 16), 256, 0, stream>>>(kbf, pj, nullptr, nullptr, nullptr, pmaxb);
        reduce_max_kernel<<<1, 256, 0, stream>>>(pmaxb, stabb, 1024);
        // fused k-exp + ksum + ctx
        hipMemsetAsync(ws + ksum_off, 0, zero_bytes, stream);
        ctx_fused_kernel<<<dim3(5, 16, 8), 256, 0, stream>>>(kbf, vT, pj, stabb, ksum, ctxT);
        // q-side fully fused (dash + rowmax + exp + denom)
        phi_row_kernel<0><<<dim3(64, 16), 256, 0, stream>>>(qbf, pj, ksum, qp, denomb, nullptr);
        // attn out
        cast_row_kernel<<<272, 256, 0, stream>>>((const float4*)ctxT, (ushort4*)ctxTbf, 16 * 64 * 272 / 4);
        attn_mfma_kernel<<<dim3(32, 16), 256, 0, stream>>>(qp, ctxTbf, denomb, abf);
        // Wo + residual + LN2 fused (64-row blocks, 512 threads / 8 waves)
        gemm_fullrow_kernel<0><<<256, 512, 0, stream>>>(abf, Wot + (size_t)i * 65536,
            bo + i * 256, xbuf, ln2g + i * 256, ln2b + i * 256, hbf,
            nullptr, nullptr, nullptr, nullptr, 256);
        // FFN
        ffn1_kernel<<<dim3(16, 128), 256, 0, stream>>>(hbf, W1t + (size_t)i * 262144,
            b1 + i * 1024, midbf, 1024, 256);
        if (i < 3)
            gemm_fullrow_kernel<0><<<256, 512, 0, stream>>>(midbf, W2t + (size_t)i * 262144,
                b2 + i * 256, xbuf, ln1g + (i + 1) * 256, ln1b + (i + 1) * 256, hbf,
                nullptr, nullptr, nullptr, nullptr, 1024);
        else
            gemm_fullrow_kernel<1><<<256, 512, 0, stream>>>(midbf, W2t + (size_t)i * 262144,
                b2 + i * 256, xbuf, nullptr, nullptr, hbf,
                nullptr, nullptr, nullptr, nullptr, 1024);
    }

    // ---- attention pooling (score fused into GEMM) ----
    gemm_fullrow_kernel<2><<<256, 512, 0, stream>>>(hbf, p1t, p1b, nullptr, nullptr, nullptr,
        nullptr, p2w, p2b, mask, alphab, 256);
    pool_denom_kernel<<<4, 256, 0, stream>>>(alphab, pdenom);
    hipMemsetAsync(d_out, 0, (size_t)out_size * sizeof(float), stream);
    pool_out_kernel<<<dim3(4, 32), 256, 0, stream>>>(xbuf, alphab, pdenom, out);
}

// Round 9
// 917.914 us; speedup vs baseline: 1.6836x; 1.0351x over previous
//
#include <hip/hip_runtime.h>
#include <math.h>

// Performer encoder on MI355X: B=4, S=4096, D=256, H=4, DH=64, L=4, M=266.
// bf16 MFMA everywhere; fp32 residual stream / LN stats / softmax logic.
// Round 9: attention chain collapsed to 3 kernels/layer:
//   phi_kmax (dash max + zero ksum/ctxT) -> ctx_fused (inline stab reduce; k-exp+ksum+ctx)
//   -> phi_q_attn (dash+exp+denom+attn out, qp stays in LDS).
// 7 dispatches/layer (was 11); qp/denomb global buffers eliminated.

#define WS_ALIGN(x) (((x) + 255) & ~(size_t)255)

#define DN 0.35355339059327373f      // 64^-0.25
#define DIAGC 0.0625f                 // 0.5 * 64^-0.5
#define RATIO 0.06131393394849658f    // 266^-0.5
#define FEPS 1e-4f

typedef __attribute__((__ext_vector_type__(8))) __bf16 bf16x8;
typedef __attribute__((__ext_vector_type__(4))) float f32x4;

__device__ __forceinline__ float wredsum(float v) {
    v += __shfl_xor(v, 32); v += __shfl_xor(v, 16); v += __shfl_xor(v, 8);
    v += __shfl_xor(v, 4);  v += __shfl_xor(v, 2);  v += __shfl_xor(v, 1);
    return v;
}
__device__ __forceinline__ float wredmax(float v) {
    v = fmaxf(v, __shfl_xor(v, 32)); v = fmaxf(v, __shfl_xor(v, 16));
    v = fmaxf(v, __shfl_xor(v, 8));  v = fmaxf(v, __shfl_xor(v, 4));
    v = fmaxf(v, __shfl_xor(v, 2));  v = fmaxf(v, __shfl_xor(v, 1));
    return v;
}

__device__ __forceinline__ unsigned short f2bf(float f) {
    unsigned u = __builtin_bit_cast(unsigned, f);
    return (unsigned short)((u + 0x7fffu + ((u >> 16) & 1u)) >> 16);
}
__device__ __forceinline__ float blo(unsigned x) { return __builtin_bit_cast(float, x << 16); }
__device__ __forceinline__ float bhi(unsigned x) { return __builtin_bit_cast(float, x & 0xffff0000u); }
__device__ __forceinline__ float sumsq8(uint4 u) {
    float s = 0.f;
    s += blo(u.x)*blo(u.x) + bhi(u.x)*bhi(u.x);
    s += blo(u.y)*blo(u.y) + bhi(u.y)*bhi(u.y);
    s += blo(u.z)*blo(u.z) + bhi(u.z)*bhi(u.z);
    s += blo(u.w)*blo(u.w) + bhi(u.w)*bhi(u.w);
    return s;
}
__device__ __forceinline__ unsigned pack2(float a, float b) {
    return (unsigned)f2bf(a) | ((unsigned)f2bf(b) << 16);
}

// ---------------- LayerNorm (fp32 in, fp32 or bf16 out) ----------------
template <bool OBF>
__global__ __launch_bounds__(256) void add_ln_kernel(
    const float* __restrict__ in, const float* __restrict__ pos,
    const float* __restrict__ g, const float* __restrict__ bta,
    float* __restrict__ outf, unsigned short* __restrict__ outb)
{
    int row = blockIdx.x, t = threadIdx.x;
    __shared__ float sred[4];
    float v = in[(size_t)row * 256 + t];
    if (pos) v += pos[(size_t)(row & 4095) * 256 + t];
    float s = wredsum(v);
    if ((t & 63) == 0) sred[t >> 6] = s;
    __syncthreads();
    float mean = (sred[0] + sred[1] + sred[2] + sred[3]) * (1.0f / 256.0f);
    float d = v - mean;
    __syncthreads();
    float sq = wredsum(d * d);
    if ((t & 63) == 0) sred[t >> 6] = sq;
    __syncthreads();
    float var = (sred[0] + sred[1] + sred[2] + sred[3]) * (1.0f / 256.0f);
    float y = d * rsqrtf(var + 1e-12f) * g[t] + bta[t];
    if (OBF) outb[(size_t)row * 256 + t] = f2bf(y);
    else     outf[(size_t)row * 256 + t] = y;
}

// ---------------- weight cast/transpose: fp32 [R][C] -> bf16 [C][R] ----------------
__global__ __launch_bounds__(256) void cast_transpose_kernel(
    const float* __restrict__ in, unsigned short* __restrict__ out, int R, int C)
{
    __shared__ float tile[32][33];
    size_t zo = (size_t)blockIdx.z * R * C;
    int c0 = blockIdx.x * 32, r0 = blockIdx.y * 32;
    int t = threadIdx.x, tc = t & 31, tr = t >> 5;
#pragma unroll
    for (int j = 0; j < 4; j++)
        tile[tr + j * 8][tc] = in[zo + (size_t)(r0 + tr + j * 8) * C + c0 + tc];
    __syncthreads();
#pragma unroll
    for (int j = 0; j < 4; j++) {
        int cc = tr + j * 8, rr = tc;
        out[zo + (size_t)(c0 + cc) * R + r0 + rr] = f2bf(tile[rr][cc]);
    }
}

// fp32 -> bf16 elementwise (n4 = count/4)
__global__ __launch_bounds__(256) void cast_row_kernel(
    const float4* __restrict__ in, ushort4* __restrict__ out, int n4)
{
    int i = blockIdx.x * 256 + threadIdx.x;
    if (i >= n4) return;
    float4 v = in[i];
    ushort4 o; o.x = f2bf(v.x); o.y = f2bf(v.y); o.z = f2bf(v.z); o.w = f2bf(v.w);
    out[i] = o;
}

// ---------------- fused QKV GEMM (N=768 over q|k|v), K=256 ----------------
__global__ __launch_bounds__(256) void qkv_kernel(
    const unsigned short* __restrict__ A,
    const unsigned short* __restrict__ Wqt, const unsigned short* __restrict__ Wkt,
    const unsigned short* __restrict__ Wvt,
    const float* __restrict__ bq, const float* __restrict__ bk, const float* __restrict__ bv,
    unsigned short* __restrict__ qbf, unsigned short* __restrict__ kbf,
    unsigned short* __restrict__ vT)
{
    __shared__ uint4 As[128][5];
    __shared__ uint4 Bs[64][5];
    const int K = 256;
    int t = threadIdx.x;
    int bm = blockIdx.y * 128, bn = blockIdx.x * 64;
    int grp = bn >> 8, lbn = bn & 255;
    const unsigned short* Bt = (grp == 0) ? Wqt : (grp == 1) ? Wkt : Wvt;
    const float* bias = (grp == 0) ? bq : (grp == 1) ? bk : bv;
    int w = t >> 6, l = t & 63, lm16 = l & 15, quad = l >> 4;
    int ar = t >> 1, ak = (t & 1) * 16;
    int br = t >> 2, bk2 = (t & 3) * 8;
    const unsigned short* Ab = A + (size_t)(bm + ar) * K + ak;
    const unsigned short* Bb = Bt + (size_t)(lbn + br) * K + bk2;
    f32x4 acc[2][4] = {};
    for (int k0 = 0; k0 < K; k0 += 32) {
        uint4 a0 = *(const uint4*)(Ab + k0);
        uint4 a1 = *(const uint4*)(Ab + k0 + 8);
        uint4 b0 = *(const uint4*)(Bb + k0);
        __syncthreads();
        As[ar][(ak >> 3)] = a0; As[ar][(ak >> 3) + 1] = a1;
        Bs[br][bk2 >> 3] = b0;
        __syncthreads();
        bf16x8 af[2], bfr[4];
        af[0] = *(const bf16x8*)&As[w * 32 + lm16][quad];
        af[1] = *(const bf16x8*)&As[w * 32 + 16 + lm16][quad];
#pragma unroll
        for (int j = 0; j < 4; j++) bfr[j] = *(const bf16x8*)&Bs[j * 16 + lm16][quad];
#pragma unroll
        for (int i = 0; i < 2; i++)
#pragma unroll
            for (int j = 0; j < 4; j++)
                acc[i][j] = __builtin_amdgcn_mfma_f32_16x16x32_bf16(af[i], bfr[j], acc[i][j], 0, 0, 0);
    }
#pragma unroll
    for (int i = 0; i < 2; i++)
#pragma unroll
        for (int j = 0; j < 4; j++) {
            int lcol = lbn + j * 16 + lm16;
            float bs = bias[lcol];
            int h = lcol >> 6, e = lcol & 63;
#pragma unroll
            for (int r = 0; r < 4; r++) {
                int row = bm + w * 32 + i * 16 + quad * 4 + r;
                int b = row >> 12, s = row & 4095;
                float v = acc[i][j][r] + bs;
                if (grp == 0)
                    qbf[((size_t)((b << 2) + h) * 4096 + s) * 64 + e] = f2bf(v);
                else if (grp == 1)
                    kbf[((size_t)((b << 2) + h) * 4096 + s) * 64 + e] = f2bf(v);
                else
                    vT[((size_t)((b << 2) + h) * 64 + e) * 4096 + s] = f2bf(v);
            }
        }
}

// ---------------- FFN1 GEMM: gelu(tanh) epilogue, bf16 out ----------------
__global__ __launch_bounds__(256) void ffn1_kernel(
    const unsigned short* __restrict__ A, const unsigned short* __restrict__ Bt,
    const float* __restrict__ bias, unsigned short* __restrict__ Cb, int N, int K)
{
    __shared__ uint4 As[128][5];
    __shared__ uint4 Bs[64][5];
    int t = threadIdx.x;
    int bm = blockIdx.y * 128, bn = blockIdx.x * 64;
    int w = t >> 6, l = t & 63, lm16 = l & 15, quad = l >> 4;
    int ar = t >> 1, ak = (t & 1) * 16;
    int br = t >> 2, bk = (t & 3) * 8;
    const unsigned short* Ab = A + (size_t)(bm + ar) * K + ak;
    const unsigned short* Bb = Bt + (size_t)(bn + br) * K + bk;
    f32x4 acc[2][4] = {};
    for (int k0 = 0; k0 < K; k0 += 32) {
        uint4 a0 = *(const uint4*)(Ab + k0);
        uint4 a1 = *(const uint4*)(Ab + k0 + 8);
        uint4 b0 = *(const uint4*)(Bb + k0);
        __syncthreads();
        As[ar][(ak >> 3)] = a0; As[ar][(ak >> 3) + 1] = a1;
        Bs[br][bk >> 3] = b0;
        __syncthreads();
        bf16x8 af[2], bfr[4];
        af[0] = *(const bf16x8*)&As[w * 32 + lm16][quad];
        af[1] = *(const bf16x8*)&As[w * 32 + 16 + lm16][quad];
#pragma unroll
        for (int j = 0; j < 4; j++) bfr[j] = *(const bf16x8*)&Bs[j * 16 + lm16][quad];
#pragma unroll
        for (int i = 0; i < 2; i++)
#pragma unroll
            for (int j = 0; j < 4; j++)
                acc[i][j] = __builtin_amdgcn_mfma_f32_16x16x32_bf16(af[i], bfr[j], acc[i][j], 0, 0, 0);
    }
#pragma unroll
    for (int i = 0; i < 2; i++)
#pragma unroll
        for (int j = 0; j < 4; j++) {
            int col = bn + j * 16 + lm16;
            float bsv = bias[col];
#pragma unroll
            for (int r = 0; r < 4; r++) {
                int row = bm + w * 32 + i * 16 + quad * 4 + r;
                float v = acc[i][j][r] + bsv;
                float inner = 0.7978845608028654f * (v + 0.044715f * v * v * v);
                float gl = 0.5f * v * (1.0f + tanhf(inner));
                Cb[(size_t)row * N + col] = f2bf(gl);
            }
        }
}

// ---------------- fused full-row GEMM: 64 rows x N=256 per block, 512 threads ----------
template <int EPI>
__global__ __launch_bounds__(512) void gemm_fullrow_kernel(
    const unsigned short* __restrict__ A, const unsigned short* __restrict__ Bt,
    const float* __restrict__ bias, float* __restrict__ xio,
    const float* __restrict__ lng, const float* __restrict__ lnb,
    unsigned short* __restrict__ outb,
    const float* __restrict__ p2w, const float* __restrict__ p2b,
    const float* __restrict__ mask, float* __restrict__ alphab, int K)
{
    __shared__ uint4 As4[64][5];
    __shared__ uint4 Bs4[256][5];
    __shared__ float red[8][64];
    int t = threadIdx.x;
    int bm = blockIdx.x * 64;
    int w = t >> 6, l = t & 63, lm16 = l & 15, quad = l >> 4;
    int br = t >> 2, bj = t & 3;
    f32x4 acc[4][2] = {};
    for (int k0 = 0; k0 < K; k0 += 32) {
        uint4 a = {0, 0, 0, 0};
        if (t < 256) a = *(const uint4*)(A + (size_t)(bm + (t >> 2)) * K + k0 + (t & 3) * 8);
        uint4 b0 = *(const uint4*)(Bt + (size_t)br * K + k0 + bj * 8);
        uint4 b1 = *(const uint4*)(Bt + (size_t)(br + 128) * K + k0 + bj * 8);
        __syncthreads();
        if (t < 256) As4[t >> 2][t & 3] = a;
        Bs4[br][bj] = b0;
        Bs4[br + 128][bj] = b1;
        __syncthreads();
        bf16x8 af[4], bfv[2];
#pragma unroll
        for (int i = 0; i < 4; i++) af[i] = *(const bf16x8*)&As4[i * 16 + lm16][quad];
#pragma unroll
        for (int j = 0; j < 2; j++) bfv[j] = *(const bf16x8*)&Bs4[w * 32 + j * 16 + lm16][quad];
#pragma unroll
        for (int i = 0; i < 4; i++)
#pragma unroll
            for (int j = 0; j < 2; j++)
                acc[i][j] = __builtin_amdgcn_mfma_f32_16x16x32_bf16(af[i], bfv[j], acc[i][j], 0, 0, 0);
    }
    int colbase = w * 32;
    if (EPI == 2) {
        float rs[4][4] = {};
#pragma unroll
        for (int j = 0; j < 2; j++) {
            int col = colbase + j * 16 + lm16;
            float bs = bias[col], pw = p2w[col];
#pragma unroll
            for (int i = 0; i < 4; i++)
#pragma unroll
                for (int r = 0; r < 4; r++)
                    rs[i][r] += tanhf(acc[i][j][r] + bs) * pw;
        }
#pragma unroll
        for (int m2 = 1; m2 <= 8; m2 <<= 1)
#pragma unroll
            for (int i = 0; i < 4; i++)
#pragma unroll
                for (int r = 0; r < 4; r++) rs[i][r] += __shfl_xor(rs[i][r], m2);
        __syncthreads();
        if (lm16 == 0) {
#pragma unroll
            for (int i = 0; i < 4; i++)
#pragma unroll
                for (int r = 0; r < 4; r++) red[w][i * 16 + quad * 4 + r] = rs[i][r];
        }
        __syncthreads();
        if (t < 64) {
            float sc = p2b[0];
#pragma unroll
            for (int ww = 0; ww < 8; ww++) sc += red[ww][t];
            int row = bm + t;
            alphab[row] = expf(sc) * mask[row];
        }
        return;
    }
    float rs[4][4] = {};
#pragma unroll
    for (int j = 0; j < 2; j++) {
        int col = colbase + j * 16 + lm16;
        float bs = bias[col];
#pragma unroll
        for (int i = 0; i < 4; i++)
#pragma unroll
            for (int r = 0; r < 4; r++) {
                int row = bm + i * 16 + quad * 4 + r;
                float v = acc[i][j][r] + bs + xio[(size_t)row * 256 + col];
                acc[i][j][r] = v;
                rs[i][r] += v;
            }
    }
    float mean[4][4], rstd[4][4];
    if (EPI == 0) {
#pragma unroll
        for (int m2 = 1; m2 <= 8; m2 <<= 1)
#pragma unroll
            for (int i = 0; i < 4; i++)
#pragma unroll
                for (int r = 0; r < 4; r++) rs[i][r] += __shfl_xor(rs[i][r], m2);
        __syncthreads();
        if (lm16 == 0) {
#pragma unroll
            for (int i = 0; i < 4; i++)
#pragma unroll
                for (int r = 0; r < 4; r++) red[w][i * 16 + quad * 4 + r] = rs[i][r];
        }
        __syncthreads();
        float vs[4][4] = {};
#pragma unroll
        for (int i = 0; i < 4; i++)
#pragma unroll
            for (int r = 0; r < 4; r++) {
                int rr = i * 16 + quad * 4 + r;
                float s = 0.f;
#pragma unroll
                for (int ww = 0; ww < 8; ww++) s += red[ww][rr];
                mean[i][r] = s * (1.0f / 256.0f);
            }
#pragma unroll
        for (int j = 0; j < 2; j++)
#pragma unroll
            for (int i = 0; i < 4; i++)
#pragma unroll
                for (int r = 0; r < 4; r++) {
                    float d = acc[i][j][r] - mean[i][r];
                    vs[i][r] += d * d;
                }
#pragma unroll
        for (int m2 = 1; m2 <= 8; m2 <<= 1)
#pragma unroll
            for (int i = 0; i < 4; i++)
#pragma unroll
                for (int r = 0; r < 4; r++) vs[i][r] += __shfl_xor(vs[i][r], m2);
        __syncthreads();
        if (lm16 == 0) {
#pragma unroll
            for (int i = 0; i < 4; i++)
#pragma unroll
                for (int r = 0; r < 4; r++) red[w][i * 16 + quad * 4 + r] = vs[i][r];
        }
        __syncthreads();
#pragma unroll
        for (int i = 0; i < 4; i++)
#pragma unroll
            for (int r = 0; r < 4; r++) {
                int rr = i * 16 + quad * 4 + r;
                float s = 0.f;
#pragma unroll
                for (int ww = 0; ww < 8; ww++) s += red[ww][rr];
                rstd[i][r] = rsqrtf(s * (1.0f / 256.0f) + 1e-12f);
            }
    }
#pragma unroll
    for (int j = 0; j < 2; j++) {
        int col = colbase + j * 16 + lm16;
        float g  = (EPI == 0) ? lng[col] : 0.f;
        float bb = (EPI == 0) ? lnb[col] : 0.f;
#pragma unroll
        for (int i = 0; i < 4; i++)
#pragma unroll
            for (int r = 0; r < 4; r++) {
                int row = bm + i * 16 + quad * 4 + r;
                float v = acc[i][j][r];
                xio[(size_t)row * 256 + col] = v;
                float y = (EPI == 0) ? ((v - mean[i][r]) * rstd[i][r] * g + bb) : v;
                outb[(size_t)row * 256 + col] = f2bf(y);
            }
    }
}

// ---------------- k-max kernel: dash block-max -> pmax; also zeros ksum+ctxT ----------------
#define ZERO_FLOATS 282880   // (16*272 + 16*64*272) floats, contiguous ksum..ctxT
__global__ __launch_bounds__(256) void phi_kmax_kernel(
    const unsigned short* __restrict__ kbf, const unsigned short* __restrict__ projbf,
    float* __restrict__ pmax, float* __restrict__ zbase)
{
    __shared__ uint4 As[64][9];
    __shared__ uint4 Bs[272][9];
    __shared__ float diag_s[64];
    __shared__ float sred[4];
    int t = threadIdx.x;
    int s0 = blockIdx.x * 64;
    int bh = blockIdx.y;
    // zero ksum+ctxT (runs before ctx_fused in stream order)
    {
        int bid = blockIdx.y * 64 + blockIdx.x;
        for (int i = bid * 256 + t; i < ZERO_FLOATS; i += 1024 * 256) zbase[i] = 0.f;
    }
    {
        int arow = t >> 2, akoff = (t & 3) * 16;
        const uint4* ga = (const uint4*)(kbf + ((size_t)bh * 4096 + s0 + arow) * 64 + akoff);
        uint4 u0 = ga[0], u1 = ga[1];
        As[arow][(akoff >> 3)] = u0; As[arow][(akoff >> 3) + 1] = u1;
        float ss = sumsq8(u0) + sumsq8(u1);
        ss += __shfl_xor(ss, 1); ss += __shfl_xor(ss, 2);
        if ((t & 3) == 0) diag_s[arow] = DIAGC * ss;
        uint4 zero = {0, 0, 0, 0};
        for (int row = t; row < 272; row += 256) {
            const uint4* gp = (const uint4*)(projbf + (size_t)row * 64);
            bool bv = row < 266;
#pragma unroll
            for (int i2 = 0; i2 < 8; i2++) Bs[row][i2] = bv ? gp[i2] : zero;
        }
    }
    __syncthreads();
    int w = t >> 6, l = t & 63, lm16 = l & 15, quad = l >> 4;
    f32x4 acc[17] = {};
#pragma unroll
    for (int ks = 0; ks < 2; ks++) {
        bf16x8 af = *(const bf16x8*)&As[w * 16 + lm16][ks * 4 + quad];
#pragma unroll
        for (int j = 0; j < 17; j++) {
            bf16x8 bfv = *(const bf16x8*)&Bs[j * 16 + lm16][ks * 4 + quad];
            acc[j] = __builtin_amdgcn_mfma_f32_16x16x32_bf16(af, bfv, acc[j], 0, 0, 0);
        }
    }
    int rloc = w * 16 + quad * 4;
    float kmax = -1e30f;
#pragma unroll
    for (int j = 0; j < 17; j++) {
        int m = j * 16 + lm16;
        bool valid = m < 266;
#pragma unroll
        for (int r = 0; r < 4; r++)
            if (valid) kmax = fmaxf(kmax, acc[j][r] * DN - diag_s[rloc + r]);
    }
    kmax = wredmax(kmax);
    if (l == 0) sred[w] = kmax;
    __syncthreads();
    if (t == 0)
        pmax[(size_t)bh * 64 + blockIdx.x] =
            fmaxf(fmaxf(sred[0], sred[1]), fmaxf(sred[2], sred[3]));
}

// ---------------- fused ctx: inline stab reduce; dash->exp->LDS->ctx MFMA + ksum ------------
__global__ __launch_bounds__(256) void ctx_fused_kernel(
    const unsigned short* __restrict__ kbf, const unsigned short* __restrict__ vT,
    const unsigned short* __restrict__ projbf, const float* __restrict__ pmax,
    float* __restrict__ ksum, float* __restrict__ ctxT)
{
    __shared__ uint4 Ap[64][9];               // proj tile [m_loc][k]
    __shared__ uint4 Ks[64][9];               // k chunk   [s_loc][k]
    __shared__ uint4 Vs[64][9];               // v chunk   [e][s_loc]
    __shared__ unsigned short kp_s[64][72];   // kp tile   [m_loc][s_loc]
    __shared__ float diag_s[64];
    __shared__ float sred2[4];
    int t = threadIdx.x;
    int m0 = blockIdx.x * 64;
    int bh = blockIdx.y;
    int sb = blockIdx.z * 512;
    int w = t >> 6, l = t & 63, lm16 = l & 15, quad = l >> 4;
    {
        int row = t >> 2, koff = (t & 3) * 16;
        uint4 zero = {0, 0, 0, 0};
        bool bv = (m0 + row) < 266;
        const uint4* gp = (const uint4*)(projbf + (size_t)(m0 + row) * 64 + koff);
        Ap[row][(koff >> 3)] = bv ? gp[0] : zero;
        Ap[row][(koff >> 3) + 1] = bv ? gp[1] : zero;
    }
    // inline stabilizer reduce (pmax[1024] -> st)
    float pm = -1e30f;
    for (int i = t; i < 1024; i += 256) pm = fmaxf(pm, pmax[i]);
    pm = wredmax(pm);
    if (l == 0) sred2[w] = pm;
    __syncthreads();
    float st = fmaxf(fmaxf(sred2[0], sred2[1]), fmaxf(sred2[2], sred2[3]));
    f32x4 accc[4] = {};
    float ksacc[4] = {0.f, 0.f, 0.f, 0.f};
    int srow = t >> 2, skoff = (t & 3) * 16;
    for (int kc = 0; kc < 8; kc++) {
        int sc = sb + kc * 64;
        const uint4* gk = (const uint4*)(kbf + ((size_t)bh * 4096 + sc + srow) * 64 + skoff);
        uint4 k0 = gk[0], k1 = gk[1];
        const uint4* gv = (const uint4*)(vT + ((size_t)bh * 64 + srow) * 4096 + sc + skoff);
        uint4 v0 = gv[0], v1 = gv[1];
        __syncthreads();
        Ks[srow][(skoff >> 3)] = k0; Ks[srow][(skoff >> 3) + 1] = k1;
        Vs[srow][(skoff >> 3)] = v0; Vs[srow][(skoff >> 3) + 1] = v1;
        float ss = sumsq8(k0) + sumsq8(k1);
        ss += __shfl_xor(ss, 1); ss += __shfl_xor(ss, 2);
        if ((t & 3) == 0) diag_s[srow] = DIAGC * ss;
        __syncthreads();
        f32x4 accd[4] = {};
#pragma unroll
        for (int ks = 0; ks < 2; ks++) {
            bf16x8 af = *(const bf16x8*)&Ap[w * 16 + lm16][ks * 4 + quad];
#pragma unroll
            for (int j = 0; j < 4; j++) {
                bf16x8 bfv = *(const bf16x8*)&Ks[j * 16 + lm16][ks * 4 + quad];
                accd[j] = __builtin_amdgcn_mfma_f32_16x16x32_bf16(af, bfv, accd[j], 0, 0, 0);
            }
        }
        int mbase = m0 + w * 16 + quad * 4;
#pragma unroll
        for (int j = 0; j < 4; j++) {
            int s_loc = j * 16 + lm16;
            float dgv = diag_s[s_loc];
#pragma unroll
            for (int r = 0; r < 4; r++) {
                float v = accd[j][r] * DN - dgv;
                float e = (mbase + r < 266) ? RATIO * (expf(v - st) + FEPS) : 0.f;
                kp_s[w * 16 + quad * 4 + r][s_loc] = f2bf(e);
                ksacc[r] += e;
            }
        }
        __syncthreads();
#pragma unroll
        for (int ks = 0; ks < 2; ks++) {
            bf16x8 af = *(const bf16x8*)&Vs[w * 16 + lm16][ks * 4 + quad];
#pragma unroll
            for (int jt = 0; jt < 4; jt++) {
                bf16x8 bfv = *(const bf16x8*)&kp_s[jt * 16 + lm16][ks * 32 + quad * 8];
                accc[jt] = __builtin_amdgcn_mfma_f32_16x16x32_bf16(af, bfv, accc[jt], 0, 0, 0);
            }
        }
    }
#pragma unroll
    for (int r = 0; r < 4; r++) {
        float v = ksacc[r];
        v += __shfl_xor(v, 1); v += __shfl_xor(v, 2);
        v += __shfl_xor(v, 4); v += __shfl_xor(v, 8);
        if (lm16 == 0) {
            int m = m0 + w * 16 + quad * 4 + r;
            if (m < 272) atomicAdd(&ksum[bh * 272 + m], v);
        }
    }
#pragma unroll
    for (int jt = 0; jt < 4; jt++) {
        int m = m0 + jt * 16 + lm16;
        if (m >= 272) continue;
#pragma unroll
        for (int r = 0; r < 4; r++) {
            int e = w * 16 + quad * 4 + r;
            atomicAdd(&ctxT[((size_t)bh * 64 + e) * 272 + m], accc[jt][r]);
        }
    }
}

// ---------------- fused q-side: dash -> rowmax -> exp -> denom -> attn out ----------------
// 64 s x 272 m per block; qp kept in LDS (A-layout), ctx streamed fp32->bf16 in k-chunks.
__global__ __launch_bounds__(256) void phi_q_attn_kernel(
    const unsigned short* __restrict__ qbf, const unsigned short* __restrict__ projbf,
    const float* __restrict__ ksum, const float* __restrict__ ctxT,
    unsigned short* __restrict__ abf)
{
    __shared__ uint4 bufA[64][9];      // stage1: q rows; stage2: ctx chunk [64][5]
    __shared__ uint4 bufB[272][9];     // stage1: proj;   stage2: qp tile ushort[64][280]
    __shared__ float diag_s[64];
    __shared__ float ks_s[272];
    __shared__ float den_s[64];
    int t = threadIdx.x;
    int s0 = blockIdx.x * 64;
    int bh = blockIdx.y;
    int w = t >> 6, l = t & 63, lm16 = l & 15, quad = l >> 4;
    {
        int arow = t >> 2, akoff = (t & 3) * 16;
        const uint4* ga = (const uint4*)(qbf + ((size_t)bh * 4096 + s0 + arow) * 64 + akoff);
        uint4 u0 = ga[0], u1 = ga[1];
        bufA[arow][(akoff >> 3)] = u0; bufA[arow][(akoff >> 3) + 1] = u1;
        float ss = sumsq8(u0) + sumsq8(u1);
        ss += __shfl_xor(ss, 1); ss += __shfl_xor(ss, 2);
        if ((t & 3) == 0) diag_s[arow] = DIAGC * ss;
        uint4 zero = {0, 0, 0, 0};
        for (int row = t; row < 272; row += 256) {
            const uint4* gp = (const uint4*)(projbf + (size_t)row * 64);
            bool bv = row < 266;
#pragma unroll
            for (int i2 = 0; i2 < 8; i2++) bufB[row][i2] = bv ? gp[i2] : zero;
        }
        ks_s[t] = ksum[bh * 272 + t];
        if (t < 16) ks_s[256 + t] = ksum[bh * 272 + 256 + t];
    }
    __syncthreads();
    // dash MFMA
    f32x4 acc[17] = {};
#pragma unroll
    for (int ks = 0; ks < 2; ks++) {
        bf16x8 af = *(const bf16x8*)&bufA[w * 16 + lm16][ks * 4 + quad];
#pragma unroll
        for (int j = 0; j < 17; j++) {
            bf16x8 bfv = *(const bf16x8*)&bufB[j * 16 + lm16][ks * 4 + quad];
            acc[j] = __builtin_amdgcn_mfma_f32_16x16x32_bf16(af, bfv, acc[j], 0, 0, 0);
        }
    }
    int rloc = w * 16 + quad * 4;
    float dg[4];
#pragma unroll
    for (int r = 0; r < 4; r++) dg[r] = diag_s[rloc + r];
    float vmax[4] = {-1e30f, -1e30f, -1e30f, -1e30f};
#pragma unroll
    for (int j = 0; j < 17; j++) {
        int m = j * 16 + lm16;
        bool valid = m < 266;
#pragma unroll
        for (int r = 0; r < 4; r++) {
            float v = acc[j][r] * DN - dg[r];
            acc[j][r] = v;
            if (valid) vmax[r] = fmaxf(vmax[r], v);
        }
    }
#pragma unroll
    for (int m2 = 1; m2 <= 8; m2 <<= 1)
#pragma unroll
        for (int r = 0; r < 4; r++) vmax[r] = fmaxf(vmax[r], __shfl_xor(vmax[r], m2));
    __syncthreads();   // all waves done reading proj from bufB
    unsigned short* qp_s = (unsigned short*)bufB;   // [64][280]
    float den[4] = {0.f, 0.f, 0.f, 0.f};
#pragma unroll
    for (int j = 0; j < 17; j++) {
        int m = j * 16 + lm16;
        bool valid = m < 266;
#pragma unroll
        for (int r = 0; r < 4; r++) {
            float e = valid ? RATIO * (expf(acc[j][r] - vmax[r]) + FEPS) : 0.f;
            qp_s[(rloc + r) * 280 + m] = f2bf(e);
            den[r] += e * ks_s[m];
        }
    }
#pragma unroll
    for (int m2 = 1; m2 <= 8; m2 <<= 1)
#pragma unroll
        for (int r = 0; r < 4; r++) den[r] += __shfl_xor(den[r], m2);
    if (lm16 == 0) {
#pragma unroll
        for (int r = 0; r < 4; r++) den_s[rloc + r] = den[r];
    }
    __syncthreads();
    // attn: out[s][e] = qp[s,:] . ctxT[e,:] / den[s]
    uint4* ctx_s = &bufA[0][0];   // [64][5] per k-chunk
    const float* ctxb = ctxT + (size_t)bh * 64 * 272;
    f32x4 oacc[4] = {};
    int ce = t >> 2, cj = t & 3;
    for (int k0 = 0; k0 < 272; k0 += 32) {
        int m = k0 + cj * 8;
        uint4 pk = {0, 0, 0, 0};
        if (m < 272) {
            const float* src = ctxb + (size_t)ce * 272 + m;
            float4 f0 = *(const float4*)(src);
            float4 f1 = *(const float4*)(src + 4);
            pk.x = pack2(f0.x, f0.y); pk.y = pack2(f0.z, f0.w);
            pk.z = pack2(f1.x, f1.y); pk.w = pack2(f1.z, f1.w);
        }
        __syncthreads();
        ctx_s[ce * 5 + cj] = pk;
        __syncthreads();
        bf16x8 af = *(const bf16x8*)&qp_s[(w * 16 + lm16) * 280 + k0 + quad * 8];
#pragma unroll
        for (int jt = 0; jt < 4; jt++) {
            bf16x8 bfv = *(const bf16x8*)&ctx_s[(jt * 16 + lm16) * 5 + quad];
            oacc[jt] = __builtin_amdgcn_mfma_f32_16x16x32_bf16(af, bfv, oacc[jt], 0, 0, 0);
        }
    }
    int b = bh >> 2, h = bh & 3;
#pragma unroll
    for (int jt = 0; jt < 4; jt++) {
        int e = jt * 16 + lm16;
#pragma unroll
        for (int r = 0; r < 4; r++) {
            int sl = w * 16 + quad * 4 + r;
            float v = oacc[jt][r] / den_s[sl];
            abf[((size_t)(b * 4096 + s0 + sl)) * 256 + h * 64 + e] = f2bf(v);
        }
    }
}

// ---------------- pooling tail ----------------
__global__ __launch_bounds__(256) void pool_denom_kernel(
    const float* __restrict__ alpha, float* __restrict__ denomb)
{
    __shared__ float sred[4];
    int b = blockIdx.x, t = threadIdx.x;
    float p = 0.f;
    for (int s = t; s < 4096; s += 256) p += alpha[b * 4096 + s];
    p = wredsum(p);
    if ((t & 63) == 0) sred[t >> 6] = p;
    __syncthreads();
    if (t == 0) denomb[b] = sred[0] + sred[1] + sred[2] + sred[3] + 1e-8f;
}

__global__ __launch_bounds__(256) void pool_out_kernel(
    const float* __restrict__ x, const float* __restrict__ alpha,
    const float* __restrict__ denomb, float* __restrict__ out)
{
    int b = blockIdx.x, chunk = blockIdx.y, t = threadIdx.x;
    float inv = 1.0f / denomb[b];
    float acc = 0.f;
    int s0 = chunk * 128;
    for (int s = s0; s < s0 + 128; s++)
        acc += x[((size_t)(b << 12) + s) * 256 + t] * alpha[(b << 12) + s];
    atomicAdd(&out[b * 256 + t], acc * inv);
}

extern "C" void kernel_launch(void* const* d_in, const int* in_sizes, int n_in,
                              void* d_out, int out_size, void* d_ws, size_t ws_size,
                              hipStream_t stream)
{
    const float* input_embs = (const float*)d_in[0];
    const float* mask  = (const float*)d_in[1];
    const float* pos   = (const float*)d_in[2];
    const float* ln_g  = (const float*)d_in[3];
    const float* ln_b  = (const float*)d_in[4];
    const float* proj  = (const float*)d_in[5];
    const float* Wq = (const float*)d_in[6];  const float* bq = (const float*)d_in[7];
    const float* Wk = (const float*)d_in[8];  const float* bk = (const float*)d_in[9];
    const float* Wv = (const float*)d_in[10]; const float* bv = (const float*)d_in[11];
    const float* Wo = (const float*)d_in[12]; const float* bo = (const float*)d_in[13];
    const float* ln1g = (const float*)d_in[14]; const float* ln1b = (const float*)d_in[15];
    const float* W1 = (const float*)d_in[16]; const float* b1 = (const float*)d_in[17];
    const float* W2 = (const float*)d_in[18]; const float* b2 = (const float*)d_in[19];
    const float* ln2g = (const float*)d_in[20]; const float* ln2b = (const float*)d_in[21];
    const float* p1w = (const float*)d_in[22]; const float* p1b = (const float*)d_in[23];
    const float* p2w = (const float*)d_in[24]; const float* p2b = (const float*)d_in[25];
    float* out = (float*)d_out;
    char* ws = (char*)d_ws;

    size_t off = 0;
    auto alloc = [&](size_t bytes) { size_t o = off; off += WS_ALIGN(bytes); return o; };
    float* xbuf = (float*)(ws + alloc(16384ull * 256 * 4));
    unsigned short* hbf = (unsigned short*)(ws + alloc(16384ull * 256 * 2));   // ln-out / attn-out
    unsigned short* qbf = (unsigned short*)(ws + alloc(16384ull * 256 * 2));
    unsigned short* kbf = (unsigned short*)(ws + alloc(16384ull * 256 * 2));
    unsigned short* vT  = (unsigned short*)(ws + alloc(16384ull * 256 * 2));
    unsigned short* midbf = (unsigned short*)(ws + alloc(16384ull * 1024 * 2)); // FFN mid
    size_t ksum_off = alloc(16ull * 272 * 4);        // ksum..ctxT contiguous, zeroed in phi_kmax
    float* ksum = (float*)(ws + ksum_off);
    float* ctxT = (float*)(ws + alloc(16ull * 64 * 272 * 4));
    float* pmaxb = (float*)(ws + alloc(1024ull * 4));
    float* alphab = (float*)(ws + alloc(16384ull * 4));
    float* pdenom = (float*)(ws + alloc(256));
    unsigned short* Wqt = (unsigned short*)(ws + alloc(4ull * 65536 * 2));
    unsigned short* Wkt = (unsigned short*)(ws + alloc(4ull * 65536 * 2));
    unsigned short* Wvt = (unsigned short*)(ws + alloc(4ull * 65536 * 2));
    unsigned short* Wot = (unsigned short*)(ws + alloc(4ull * 65536 * 2));
    unsigned short* W1t = (unsigned short*)(ws + alloc(4ull * 262144 * 2));
    unsigned short* W2t = (unsigned short*)(ws + alloc(4ull * 262144 * 2));
    unsigned short* projbf = (unsigned short*)(ws + alloc(4ull * 17024 * 2));
    unsigned short* p1t = (unsigned short*)(ws + alloc(65536ull * 2));
    unsigned short* abf = hbf;
    // total ~93 MB (< 256 MiB)

    // ---- weight casts (all layers up front) ----
    cast_transpose_kernel<<<dim3(8, 8, 4), 256, 0, stream>>>(Wq, Wqt, 256, 256);
    cast_transpose_kernel<<<dim3(8, 8, 4), 256, 0, stream>>>(Wk, Wkt, 256, 256);
    cast_transpose_kernel<<<dim3(8, 8, 4), 256, 0, stream>>>(Wv, Wvt, 256, 256);
    cast_transpose_kernel<<<dim3(8, 8, 4), 256, 0, stream>>>(Wo, Wot, 256, 256);
    cast_transpose_kernel<<<dim3(32, 8, 4), 256, 0, stream>>>(W1, W1t, 256, 1024);
    cast_transpose_kernel<<<dim3(8, 32, 4), 256, 0, stream>>>(W2, W2t, 1024, 256);
    cast_transpose_kernel<<<dim3(8, 8, 1), 256, 0, stream>>>(p1w, p1t, 256, 256);
    cast_row_kernel<<<67, 256, 0, stream>>>((const float4*)proj, (ushort4*)projbf, 17024);

    // ---- x = LN(input + pos); hbf = LN1_0(x) ----
    add_ln_kernel<false><<<16384, 256, 0, stream>>>(input_embs, pos, ln_g, ln_b, xbuf, nullptr);
    add_ln_kernel<true><<<16384, 256, 0, stream>>>(xbuf, nullptr, ln1g, ln1b, nullptr, hbf);

    for (int i = 0; i < 4; i++) {
        const unsigned short* pj = projbf + (size_t)i * 17024;
        // QKV fused
        qkv_kernel<<<dim3(12, 128), 256, 0, stream>>>(hbf,
            Wqt + (size_t)i * 65536, Wkt + (size_t)i * 65536, Wvt + (size_t)i * 65536,
            bq + i * 256, bk + i * 256, bv + i * 256, qbf, kbf, vT);
        // k stabilizer block-max + zero ksum/ctxT
        phi_kmax_kernel<<<dim3(64, 16), 256, 0, stream>>>(kbf, pj, pmaxb, ksum);
        // fused k-exp + ksum + ctx (inline stab reduce)
        ctx_fused_kernel<<<dim3(5, 16, 8), 256, 0, stream>>>(kbf, vT, pj, pmaxb, ksum, ctxT);
        // fused q-side: dash + exp + denom + attn out (qp stays in LDS)
        phi_q_attn_kernel<<<dim3(64, 16), 256, 0, stream>>>(qbf, pj, ksum, ctxT, abf);
        // Wo + residual + LN2 fused
        gemm_fullrow_kernel<0><<<256, 512, 0, stream>>>(abf, Wot + (size_t)i * 65536,
            bo + i * 256, xbuf, ln2g + i * 256, ln2b + i * 256, hbf,
            nullptr, nullptr, nullptr, nullptr, 256);
        // FFN
        ffn1_kernel<<<dim3(16, 128), 256, 0, stream>>>(hbf, W1t + (size_t)i * 262144,
            b1 + i * 1024, midbf, 1024, 256);
        if (i < 3)
            gemm_fullrow_kernel<0><<<256, 512, 0, stream>>>(midbf, W2t + (size_t)i * 262144,
                b2 + i * 256, xbuf, ln1g + (i + 1) * 256, ln1b + (i + 1) * 256, hbf,
                nullptr, nullptr, nullptr, nullptr, 1024);
        else
            gemm_fullrow_kernel<1><<<256, 512, 0, stream>>>(midbf, W2t + (size_t)i * 262144,
                b2 + i * 256, xbuf, nullptr, nullptr, hbf,
                nullptr, nullptr, nullptr, nullptr, 1024);
    }

    // ---- attention pooling (score fused into GEMM) ----
    gemm_fullrow_kernel<2><<<256, 512, 0, stream>>>(hbf, p1t, p1b, nullptr, nullptr, nullptr,
        nullptr, p2w, p2b, mask, alphab, 256);
    pool_denom_kernel<<<4, 256, 0, stream>>>(alphab, pdenom);
    hipMemsetAsync(d_out, 0, (size_t)out_size * sizeof(float), stream);
    pool_out_kernel<<<dim3(4, 32), 256, 0, stream>>>(xbuf, alphab, pdenom, out);
}

// Round 11
// 906.212 us; speedup vs baseline: 1.7053x; 1.0129x over previous
//
#include <hip/hip_runtime.h>
#include <math.h>

// Performer encoder on MI355X: B=4, S=4096, D=256, H=4, DH=64, L=4, M=266.
// bf16 MFMA everywhere; fp32 residual stream / LN stats / softmax logic.
// Round 11: BISECT of r10's NaN — qkv/ffn1 reverted to r9-proven 128x64 tiling;
// keeping only the two trivially-verified utility fusions (add_ln2, cast_transpose4).

#define WS_ALIGN(x) (((x) + 255) & ~(size_t)255)

#define DN 0.35355339059327373f      // 64^-0.25
#define DIAGC 0.0625f                 // 0.5 * 64^-0.5
#define RATIO 0.06131393394849658f    // 266^-0.5
#define FEPS 1e-4f

typedef __attribute__((__ext_vector_type__(8))) __bf16 bf16x8;
typedef __attribute__((__ext_vector_type__(4))) float f32x4;

__device__ __forceinline__ float wredsum(float v) {
    v += __shfl_xor(v, 32); v += __shfl_xor(v, 16); v += __shfl_xor(v, 8);
    v += __shfl_xor(v, 4);  v += __shfl_xor(v, 2);  v += __shfl_xor(v, 1);
    return v;
}
__device__ __forceinline__ float wredmax(float v) {
    v = fmaxf(v, __shfl_xor(v, 32)); v = fmaxf(v, __shfl_xor(v, 16));
    v = fmaxf(v, __shfl_xor(v, 8));  v = fmaxf(v, __shfl_xor(v, 4));
    v = fmaxf(v, __shfl_xor(v, 2));  v = fmaxf(v, __shfl_xor(v, 1));
    return v;
}

__device__ __forceinline__ unsigned short f2bf(float f) {
    unsigned u = __builtin_bit_cast(unsigned, f);
    return (unsigned short)((u + 0x7fffu + ((u >> 16) & 1u)) >> 16);
}
__device__ __forceinline__ float blo(unsigned x) { return __builtin_bit_cast(float, x << 16); }
__device__ __forceinline__ float bhi(unsigned x) { return __builtin_bit_cast(float, x & 0xffff0000u); }
__device__ __forceinline__ float sumsq8(uint4 u) {
    float s = 0.f;
    s += blo(u.x)*blo(u.x) + bhi(u.x)*bhi(u.x);
    s += blo(u.y)*blo(u.y) + bhi(u.y)*bhi(u.y);
    s += blo(u.z)*blo(u.z) + bhi(u.z)*bhi(u.z);
    s += blo(u.w)*blo(u.w) + bhi(u.w)*bhi(u.w);
    return s;
}
__device__ __forceinline__ unsigned pack2(float a, float b) {
    return (unsigned)f2bf(a) | ((unsigned)f2bf(b) << 16);
}

// ---------------- fused double LayerNorm: x = LN0(in+pos); h = bf16(LN1(x)) ----------------
__global__ __launch_bounds__(256) void add_ln2_kernel(
    const float* __restrict__ in, const float* __restrict__ pos,
    const float* __restrict__ g0, const float* __restrict__ b0,
    const float* __restrict__ g1, const float* __restrict__ b1,
    float* __restrict__ xout, unsigned short* __restrict__ hout)
{
    int row = blockIdx.x, t = threadIdx.x;
    __shared__ float sred[4];
    float v = in[(size_t)row * 256 + t] + pos[(size_t)(row & 4095) * 256 + t];
    float s = wredsum(v);
    if ((t & 63) == 0) sred[t >> 6] = s;
    __syncthreads();
    float mean = (sred[0] + sred[1] + sred[2] + sred[3]) * (1.0f / 256.0f);
    float d = v - mean;
    __syncthreads();
    float sq = wredsum(d * d);
    if ((t & 63) == 0) sred[t >> 6] = sq;
    __syncthreads();
    float var = (sred[0] + sred[1] + sred[2] + sred[3]) * (1.0f / 256.0f);
    float y1 = d * rsqrtf(var + 1e-12f) * g0[t] + b0[t];
    xout[(size_t)row * 256 + t] = y1;
    __syncthreads();
    float s1 = wredsum(y1);
    if ((t & 63) == 0) sred[t >> 6] = s1;
    __syncthreads();
    float mean1 = (sred[0] + sred[1] + sred[2] + sred[3]) * (1.0f / 256.0f);
    float d1 = y1 - mean1;
    __syncthreads();
    float sq1 = wredsum(d1 * d1);
    if ((t & 63) == 0) sred[t >> 6] = sq1;
    __syncthreads();
    float var1 = (sred[0] + sred[1] + sred[2] + sred[3]) * (1.0f / 256.0f);
    hout[(size_t)row * 256 + t] = f2bf(d1 * rsqrtf(var1 + 1e-12f) * g1[t] + b1[t]);
}

// ---------------- weight cast/transpose: fp32 [R][C] -> bf16 [C][R] ----------------
__global__ __launch_bounds__(256) void cast_transpose_kernel(
    const float* __restrict__ in, unsigned short* __restrict__ out, int R, int C)
{
    __shared__ float tile[32][33];
    size_t zo = (size_t)blockIdx.z * R * C;
    int c0 = blockIdx.x * 32, r0 = blockIdx.y * 32;
    int t = threadIdx.x, tc = t & 31, tr = t >> 5;
#pragma unroll
    for (int j = 0; j < 4; j++)
        tile[tr + j * 8][tc] = in[zo + (size_t)(r0 + tr + j * 8) * C + c0 + tc];
    __syncthreads();
#pragma unroll
    for (int j = 0; j < 4; j++) {
        int cc = tr + j * 8, rr = tc;
        out[zo + (size_t)(c0 + cc) * R + r0 + rr] = f2bf(tile[rr][cc]);
    }
}

// 4-way merged 256x256x4-layer cast/transpose (Wq,Wk,Wv,Wo in one dispatch)
__global__ __launch_bounds__(256) void cast_transpose4_kernel(
    const float* __restrict__ i0, const float* __restrict__ i1,
    const float* __restrict__ i2, const float* __restrict__ i3,
    unsigned short* __restrict__ o0, unsigned short* __restrict__ o1,
    unsigned short* __restrict__ o2, unsigned short* __restrict__ o3)
{
    __shared__ float tile[32][33];
    int z = blockIdx.z;
    int which = z >> 2, layer = z & 3;
    const float* in = (which == 0) ? i0 : (which == 1) ? i1 : (which == 2) ? i2 : i3;
    unsigned short* out = (which == 0) ? o0 : (which == 1) ? o1 : (which == 2) ? o2 : o3;
    size_t zo = (size_t)layer * 65536;
    int c0 = blockIdx.x * 32, r0 = blockIdx.y * 32;
    int t = threadIdx.x, tc = t & 31, tr = t >> 5;
#pragma unroll
    for (int j = 0; j < 4; j++)
        tile[tr + j * 8][tc] = in[zo + (size_t)(r0 + tr + j * 8) * 256 + c0 + tc];
    __syncthreads();
#pragma unroll
    for (int j = 0; j < 4; j++) {
        int cc = tr + j * 8, rr = tc;
        out[zo + (size_t)(c0 + cc) * 256 + r0 + rr] = f2bf(tile[rr][cc]);
    }
}

// fp32 -> bf16 elementwise (n4 = count/4)
__global__ __launch_bounds__(256) void cast_row_kernel(
    const float4* __restrict__ in, ushort4* __restrict__ out, int n4)
{
    int i = blockIdx.x * 256 + threadIdx.x;
    if (i >= n4) return;
    float4 v = in[i];
    ushort4 o; o.x = f2bf(v.x); o.y = f2bf(v.y); o.z = f2bf(v.z); o.w = f2bf(v.w);
    out[i] = o;
}

// ---------------- fused QKV GEMM (N=768 over q|k|v), K=256 — r9-proven 128x64 tiles ------
__global__ __launch_bounds__(256) void qkv_kernel(
    const unsigned short* __restrict__ A,
    const unsigned short* __restrict__ Wqt, const unsigned short* __restrict__ Wkt,
    const unsigned short* __restrict__ Wvt,
    const float* __restrict__ bq, const float* __restrict__ bk, const float* __restrict__ bv,
    unsigned short* __restrict__ qbf, unsigned short* __restrict__ kbf,
    unsigned short* __restrict__ vT)
{
    __shared__ uint4 As[128][5];
    __shared__ uint4 Bs[64][5];
    const int K = 256;
    int t = threadIdx.x;
    int bm = blockIdx.y * 128, bn = blockIdx.x * 64;
    int grp = bn >> 8, lbn = bn & 255;
    const unsigned short* Bt = (grp == 0) ? Wqt : (grp == 1) ? Wkt : Wvt;
    const float* bias = (grp == 0) ? bq : (grp == 1) ? bk : bv;
    int w = t >> 6, l = t & 63, lm16 = l & 15, quad = l >> 4;
    int ar = t >> 1, ak = (t & 1) * 16;
    int br = t >> 2, bk2 = (t & 3) * 8;
    const unsigned short* Ab = A + (size_t)(bm + ar) * K + ak;
    const unsigned short* Bb = Bt + (size_t)(lbn + br) * K + bk2;
    f32x4 acc[2][4] = {};
    for (int k0 = 0; k0 < K; k0 += 32) {
        uint4 a0 = *(const uint4*)(Ab + k0);
        uint4 a1 = *(const uint4*)(Ab + k0 + 8);
        uint4 b0 = *(const uint4*)(Bb + k0);
        __syncthreads();
        As[ar][(ak >> 3)] = a0; As[ar][(ak >> 3) + 1] = a1;
        Bs[br][bk2 >> 3] = b0;
        __syncthreads();
        bf16x8 af[2], bfr[4];
        af[0] = *(const bf16x8*)&As[w * 32 + lm16][quad];
        af[1] = *(const bf16x8*)&As[w * 32 + 16 + lm16][quad];
#pragma unroll
        for (int j = 0; j < 4; j++) bfr[j] = *(const bf16x8*)&Bs[j * 16 + lm16][quad];
#pragma unroll
        for (int i = 0; i < 2; i++)
#pragma unroll
            for (int j = 0; j < 4; j++)
                acc[i][j] = __builtin_amdgcn_mfma_f32_16x16x32_bf16(af[i], bfr[j], acc[i][j], 0, 0, 0);
    }
#pragma unroll
    for (int i = 0; i < 2; i++)
#pragma unroll
        for (int j = 0; j < 4; j++) {
            int lcol = lbn + j * 16 + lm16;
            float bs = bias[lcol];
            int h = lcol >> 6, e = lcol & 63;
#pragma unroll
            for (int r = 0; r < 4; r++) {
                int row = bm + w * 32 + i * 16 + quad * 4 + r;
                int b = row >> 12, s = row & 4095;
                float v = acc[i][j][r] + bs;
                if (grp == 0)
                    qbf[((size_t)((b << 2) + h) * 4096 + s) * 64 + e] = f2bf(v);
                else if (grp == 1)
                    kbf[((size_t)((b << 2) + h) * 4096 + s) * 64 + e] = f2bf(v);
                else
                    vT[((size_t)((b << 2) + h) * 64 + e) * 4096 + s] = f2bf(v);
            }
        }
}

// ---------------- FFN1 GEMM — r9-proven 128x64 tiles: gelu(tanh) epilogue, bf16 out -------
__global__ __launch_bounds__(256) void ffn1_kernel(
    const unsigned short* __restrict__ A, const unsigned short* __restrict__ Bt,
    const float* __restrict__ bias, unsigned short* __restrict__ Cb, int N, int K)
{
    __shared__ uint4 As[128][5];
    __shared__ uint4 Bs[64][5];
    int t = threadIdx.x;
    int bm = blockIdx.y * 128, bn = blockIdx.x * 64;
    int w = t >> 6, l = t & 63, lm16 = l & 15, quad = l >> 4;
    int ar = t >> 1, ak = (t & 1) * 16;
    int br = t >> 2, bk = (t & 3) * 8;
    const unsigned short* Ab = A + (size_t)(bm + ar) * K + ak;
    const unsigned short* Bb = Bt + (size_t)(bn + br) * K + bk;
    f32x4 acc[2][4] = {};
    for (int k0 = 0; k0 < K; k0 += 32) {
        uint4 a0 = *(const uint4*)(Ab + k0);
        uint4 a1 = *(const uint4*)(Ab + k0 + 8);
        uint4 b0 = *(const uint4*)(Bb + k0);
        __syncthreads();
        As[ar][(ak >> 3)] = a0; As[ar][(ak >> 3) + 1] = a1;
        Bs[br][bk >> 3] = b0;
        __syncthreads();
        bf16x8 af[2], bfr[4];
        af[0] = *(const bf16x8*)&As[w * 32 + lm16][quad];
        af[1] = *(const bf16x8*)&As[w * 32 + 16 + lm16][quad];
#pragma unroll
        for (int j = 0; j < 4; j++) bfr[j] = *(const bf16x8*)&Bs[j * 16 + lm16][quad];
#pragma unroll
        for (int i = 0; i < 2; i++)
#pragma unroll
            for (int j = 0; j < 4; j++)
                acc[i][j] = __builtin_amdgcn_mfma_f32_16x16x32_bf16(af[i], bfr[j], acc[i][j], 0, 0, 0);
    }
#pragma unroll
    for (int i = 0; i < 2; i++)
#pragma unroll
        for (int j = 0; j < 4; j++) {
            int col = bn + j * 16 + lm16;
            float bsv = bias[col];
#pragma unroll
            for (int r = 0; r < 4; r++) {
                int row = bm + w * 32 + i * 16 + quad * 4 + r;
                float v = acc[i][j][r] + bsv;
                float inner = 0.7978845608028654f * (v + 0.044715f * v * v * v);
                float gl = 0.5f * v * (1.0f + tanhf(inner));
                Cb[(size_t)row * N + col] = f2bf(gl);
            }
        }
}

// ---------------- fused full-row GEMM: 64 rows x N=256 per block, 512 threads ----------
template <int EPI>
__global__ __launch_bounds__(512) void gemm_fullrow_kernel(
    const unsigned short* __restrict__ A, const unsigned short* __restrict__ Bt,
    const float* __restrict__ bias, float* __restrict__ xio,
    const float* __restrict__ lng, const float* __restrict__ lnb,
    unsigned short* __restrict__ outb,
    const float* __restrict__ p2w, const float* __restrict__ p2b,
    const float* __restrict__ mask, float* __restrict__ alphab, int K)
{
    __shared__ uint4 As4[64][5];
    __shared__ uint4 Bs4[256][5];
    __shared__ float red[8][64];
    int t = threadIdx.x;
    int bm = blockIdx.x * 64;
    int w = t >> 6, l = t & 63, lm16 = l & 15, quad = l >> 4;
    int br = t >> 2, bj = t & 3;
    f32x4 acc[4][2] = {};
    for (int k0 = 0; k0 < K; k0 += 32) {
        uint4 a = {0, 0, 0, 0};
        if (t < 256) a = *(const uint4*)(A + (size_t)(bm + (t >> 2)) * K + k0 + (t & 3) * 8);
        uint4 b0 = *(const uint4*)(Bt + (size_t)br * K + k0 + bj * 8);
        uint4 b1 = *(const uint4*)(Bt + (size_t)(br + 128) * K + k0 + bj * 8);
        __syncthreads();
        if (t < 256) As4[t >> 2][t & 3] = a;
        Bs4[br][bj] = b0;
        Bs4[br + 128][bj] = b1;
        __syncthreads();
        bf16x8 af[4], bfv[2];
#pragma unroll
        for (int i = 0; i < 4; i++) af[i] = *(const bf16x8*)&As4[i * 16 + lm16][quad];
#pragma unroll
        for (int j = 0; j < 2; j++) bfv[j] = *(const bf16x8*)&Bs4[w * 32 + j * 16 + lm16][quad];
#pragma unroll
        for (int i = 0; i < 4; i++)
#pragma unroll
            for (int j = 0; j < 2; j++)
                acc[i][j] = __builtin_amdgcn_mfma_f32_16x16x32_bf16(af[i], bfv[j], acc[i][j], 0, 0, 0);
    }
    int colbase = w * 32;
    if (EPI == 2) {
        float rs[4][4] = {};
#pragma unroll
        for (int j = 0; j < 2; j++) {
            int col = colbase + j * 16 + lm16;
            float bs = bias[col], pw = p2w[col];
#pragma unroll
            for (int i = 0; i < 4; i++)
#pragma unroll
                for (int r = 0; r < 4; r++)
                    rs[i][r] += tanhf(acc[i][j][r] + bs) * pw;
        }
#pragma unroll
        for (int m2 = 1; m2 <= 8; m2 <<= 1)
#pragma unroll
            for (int i = 0; i < 4; i++)
#pragma unroll
                for (int r = 0; r < 4; r++) rs[i][r] += __shfl_xor(rs[i][r], m2);
        __syncthreads();
        if (lm16 == 0) {
#pragma unroll
            for (int i = 0; i < 4; i++)
#pragma unroll
                for (int r = 0; r < 4; r++) red[w][i * 16 + quad * 4 + r] = rs[i][r];
        }
        __syncthreads();
        if (t < 64) {
            float sc = p2b[0];
#pragma unroll
            for (int ww = 0; ww < 8; ww++) sc += red[ww][t];
            int row = bm + t;
            alphab[row] = expf(sc) * mask[row];
        }
        return;
    }
    float rs[4][4] = {};
#pragma unroll
    for (int j = 0; j < 2; j++) {
        int col = colbase + j * 16 + lm16;
        float bs = bias[col];
#pragma unroll
        for (int i = 0; i < 4; i++)
#pragma unroll
            for (int r = 0; r < 4; r++) {
                int row = bm + i * 16 + quad * 4 + r;
                float v = acc[i][j][r] + bs + xio[(size_t)row * 256 + col];
                acc[i][j][r] = v;
                rs[i][r] += v;
            }
    }
    float mean[4][4], rstd[4][4];
    if (EPI == 0) {
#pragma unroll
        for (int m2 = 1; m2 <= 8; m2 <<= 1)
#pragma unroll
            for (int i = 0; i < 4; i++)
#pragma unroll
                for (int r = 0; r < 4; r++) rs[i][r] += __shfl_xor(rs[i][r], m2);
        __syncthreads();
        if (lm16 == 0) {
#pragma unroll
            for (int i = 0; i < 4; i++)
#pragma unroll
                for (int r = 0; r < 4; r++) red[w][i * 16 + quad * 4 + r] = rs[i][r];
        }
        __syncthreads();
        float vs[4][4] = {};
#pragma unroll
        for (int i = 0; i < 4; i++)
#pragma unroll
            for (int r = 0; r < 4; r++) {
                int rr = i * 16 + quad * 4 + r;
                float s = 0.f;
#pragma unroll
                for (int ww = 0; ww < 8; ww++) s += red[ww][rr];
                mean[i][r] = s * (1.0f / 256.0f);
            }
#pragma unroll
        for (int j = 0; j < 2; j++)
#pragma unroll
            for (int i = 0; i < 4; i++)
#pragma unroll
                for (int r = 0; r < 4; r++) {
                    float d = acc[i][j][r] - mean[i][r];
                    vs[i][r] += d * d;
                }
#pragma unroll
        for (int m2 = 1; m2 <= 8; m2 <<= 1)
#pragma unroll
            for (int i = 0; i < 4; i++)
#pragma unroll
                for (int r = 0; r < 4; r++) vs[i][r] += __shfl_xor(vs[i][r], m2);
        __syncthreads();
        if (lm16 == 0) {
#pragma unroll
            for (int i = 0; i < 4; i++)
#pragma unroll
                for (int r = 0; r < 4; r++) red[w][i * 16 + quad * 4 + r] = vs[i][r];
        }
        __syncthreads();
#pragma unroll
        for (int i = 0; i < 4; i++)
#pragma unroll
            for (int r = 0; r < 4; r++) {
                int rr = i * 16 + quad * 4 + r;
                float s = 0.f;
#pragma unroll
                for (int ww = 0; ww < 8; ww++) s += red[ww][rr];
                rstd[i][r] = rsqrtf(s * (1.0f / 256.0f) + 1e-12f);
            }
    }
#pragma unroll
    for (int j = 0; j < 2; j++) {
        int col = colbase + j * 16 + lm16;
        float g  = (EPI == 0) ? lng[col] : 0.f;
        float bb = (EPI == 0) ? lnb[col] : 0.f;
#pragma unroll
        for (int i = 0; i < 4; i++)
#pragma unroll
            for (int r = 0; r < 4; r++) {
                int row = bm + i * 16 + quad * 4 + r;
                float v = acc[i][j][r];
                xio[(size_t)row * 256 + col] = v;
                float y = (EPI == 0) ? ((v - mean[i][r]) * rstd[i][r] * g + bb) : v;
                outb[(size_t)row * 256 + col] = f2bf(y);
            }
    }
}

// ---------------- k-max kernel: dash block-max -> pmax; also zeros ksum+ctxT ----------------
#define ZERO_FLOATS 282880   // (16*272 + 16*64*272) floats, contiguous ksum..ctxT
__global__ __launch_bounds__(256) void phi_kmax_kernel(
    const unsigned short* __restrict__ kbf, const unsigned short* __restrict__ projbf,
    float* __restrict__ pmax, float* __restrict__ zbase)
{
    __shared__ uint4 As[64][9];
    __shared__ uint4 Bs[272][9];
    __shared__ float diag_s[64];
    __shared__ float sred[4];
    int t = threadIdx.x;
    int s0 = blockIdx.x * 64;
    int bh = blockIdx.y;
    {
        int bid = blockIdx.y * 64 + blockIdx.x;
        for (int i = bid * 256 + t; i < ZERO_FLOATS; i += 1024 * 256) zbase[i] = 0.f;
    }
    {
        int arow = t >> 2, akoff = (t & 3) * 16;
        const uint4* ga = (const uint4*)(kbf + ((size_t)bh * 4096 + s0 + arow) * 64 + akoff);
        uint4 u0 = ga[0], u1 = ga[1];
        As[arow][(akoff >> 3)] = u0; As[arow][(akoff >> 3) + 1] = u1;
        float ss = sumsq8(u0) + sumsq8(u1);
        ss += __shfl_xor(ss, 1); ss += __shfl_xor(ss, 2);
        if ((t & 3) == 0) diag_s[arow] = DIAGC * ss;
        uint4 zero = {0, 0, 0, 0};
        for (int row = t; row < 272; row += 256) {
            const uint4* gp = (const uint4*)(projbf + (size_t)row * 64);
            bool bv = row < 266;
#pragma unroll
            for (int i2 = 0; i2 < 8; i2++) Bs[row][i2] = bv ? gp[i2] : zero;
        }
    }
    __syncthreads();
    int w = t >> 6, l = t & 63, lm16 = l & 15, quad = l >> 4;
    f32x4 acc[17] = {};
#pragma unroll
    for (int ks = 0; ks < 2; ks++) {
        bf16x8 af = *(const bf16x8*)&As[w * 16 + lm16][ks * 4 + quad];
#pragma unroll
        for (int j = 0; j < 17; j++) {
            bf16x8 bfv = *(const bf16x8*)&Bs[j * 16 + lm16][ks * 4 + quad];
            acc[j] = __builtin_amdgcn_mfma_f32_16x16x32_bf16(af, bfv, acc[j], 0, 0, 0);
        }
    }
    int rloc = w * 16 + quad * 4;
    float kmax = -1e30f;
#pragma unroll
    for (int j = 0; j < 17; j++) {
        int m = j * 16 + lm16;
        bool valid = m < 266;
#pragma unroll
        for (int r = 0; r < 4; r++)
            if (valid) kmax = fmaxf(kmax, acc[j][r] * DN - diag_s[rloc + r]);
    }
    kmax = wredmax(kmax);
    if (l == 0) sred[w] = kmax;
    __syncthreads();
    if (t == 0)
        pmax[(size_t)bh * 64 + blockIdx.x] =
            fmaxf(fmaxf(sred[0], sred[1]), fmaxf(sred[2], sred[3]));
}

// ---------------- fused ctx: inline stab reduce; dash->exp->LDS->ctx MFMA + ksum ------------
__global__ __launch_bounds__(256) void ctx_fused_kernel(
    const unsigned short* __restrict__ kbf, const unsigned short* __restrict__ vT,
    const unsigned short* __restrict__ projbf, const float* __restrict__ pmax,
    float* __restrict__ ksum, float* __restrict__ ctxT)
{
    __shared__ uint4 Ap[64][9];
    __shared__ uint4 Ks[64][9];
    __shared__ uint4 Vs[64][9];
    __shared__ unsigned short kp_s[64][72];
    __shared__ float diag_s[64];
    __shared__ float sred2[4];
    int t = threadIdx.x;
    int m0 = blockIdx.x * 64;
    int bh = blockIdx.y;
    int sb = blockIdx.z * 512;
    int w = t >> 6, l = t & 63, lm16 = l & 15, quad = l >> 4;
    {
        int row = t >> 2, koff = (t & 3) * 16;
        uint4 zero = {0, 0, 0, 0};
        bool bv = (m0 + row) < 266;
        const uint4* gp = (const uint4*)(projbf + (size_t)(m0 + row) * 64 + koff);
        Ap[row][(koff >> 3)] = bv ? gp[0] : zero;
        Ap[row][(koff >> 3) + 1] = bv ? gp[1] : zero;
    }
    float pm = -1e30f;
    for (int i = t; i < 1024; i += 256) pm = fmaxf(pm, pmax[i]);
    pm = wredmax(pm);
    if (l == 0) sred2[w] = pm;
    __syncthreads();
    float st = fmaxf(fmaxf(sred2[0], sred2[1]), fmaxf(sred2[2], sred2[3]));
    f32x4 accc[4] = {};
    float ksacc[4] = {0.f, 0.f, 0.f, 0.f};
    int srow = t >> 2, skoff = (t & 3) * 16;
    for (int kc = 0; kc < 8; kc++) {
        int sc = sb + kc * 64;
        const uint4* gk = (const uint4*)(kbf + ((size_t)bh * 4096 + sc + srow) * 64 + skoff);
        uint4 k0 = gk[0], k1 = gk[1];
        const uint4* gv = (const uint4*)(vT + ((size_t)bh * 64 + srow) * 4096 + sc + skoff);
        uint4 v0 = gv[0], v1 = gv[1];
        __syncthreads();
        Ks[srow][(skoff >> 3)] = k0; Ks[srow][(skoff >> 3) + 1] = k1;
        Vs[srow][(skoff >> 3)] = v0; Vs[srow][(skoff >> 3) + 1] = v1;
        float ss = sumsq8(k0) + sumsq8(k1);
        ss += __shfl_xor(ss, 1); ss += __shfl_xor(ss, 2);
        if ((t & 3) == 0) diag_s[srow] = DIAGC * ss;
        __syncthreads();
        f32x4 accd[4] = {};
#pragma unroll
        for (int ks = 0; ks < 2; ks++) {
            bf16x8 af = *(const bf16x8*)&Ap[w * 16 + lm16][ks * 4 + quad];
#pragma unroll
            for (int j = 0; j < 4; j++) {
                bf16x8 bfv = *(const bf16x8*)&Ks[j * 16 + lm16][ks * 4 + quad];
                accd[j] = __builtin_amdgcn_mfma_f32_16x16x32_bf16(af, bfv, accd[j], 0, 0, 0);
            }
        }
        int mbase = m0 + w * 16 + quad * 4;
#pragma unroll
        for (int j = 0; j < 4; j++) {
            int s_loc = j * 16 + lm16;
            float dgv = diag_s[s_loc];
#pragma unroll
            for (int r = 0; r < 4; r++) {
                float v = accd[j][r] * DN - dgv;
                float e = (mbase + r < 266) ? RATIO * (expf(v - st) + FEPS) : 0.f;
                kp_s[w * 16 + quad * 4 + r][s_loc] = f2bf(e);
                ksacc[r] += e;
            }
        }
        __syncthreads();
#pragma unroll
        for (int ks = 0; ks < 2; ks++) {
            bf16x8 af = *(const bf16x8*)&Vs[w * 16 + lm16][ks * 4 + quad];
#pragma unroll
            for (int jt = 0; jt < 4; jt++) {
                bf16x8 bfv = *(const bf16x8*)&kp_s[jt * 16 + lm16][ks * 32 + quad * 8];
                accc[jt] = __builtin_amdgcn_mfma_f32_16x16x32_bf16(af, bfv, accc[jt], 0, 0, 0);
            }
        }
    }
#pragma unroll
    for (int r = 0; r < 4; r++) {
        float v = ksacc[r];
        v += __shfl_xor(v, 1); v += __shfl_xor(v, 2);
        v += __shfl_xor(v, 4); v += __shfl_xor(v, 8);
        if (lm16 == 0) {
            int m = m0 + w * 16 + quad * 4 + r;
            if (m < 272) atomicAdd(&ksum[bh * 272 + m], v);
        }
    }
#pragma unroll
    for (int jt = 0; jt < 4; jt++) {
        int m = m0 + jt * 16 + lm16;
        if (m >= 272) continue;
#pragma unroll
        for (int r = 0; r < 4; r++) {
            int e = w * 16 + quad * 4 + r;
            atomicAdd(&ctxT[((size_t)bh * 64 + e) * 272 + m], accc[jt][r]);
        }
    }
}

// ---------------- fused q-side: dash -> rowmax -> exp -> denom -> attn out ----------------
__global__ __launch_bounds__(256) void phi_q_attn_kernel(
    const unsigned short* __restrict__ qbf, const unsigned short* __restrict__ projbf,
    const float* __restrict__ ksum, const float* __restrict__ ctxT,
    unsigned short* __restrict__ abf)
{
    __shared__ uint4 bufA[64][9];      // stage1: q rows; stage2: ctx chunk [64][5]
    __shared__ uint4 bufB[272][9];     // stage1: proj;   stage2: qp tile ushort[64][280]
    __shared__ float diag_s[64];
    __shared__ float ks_s[272];
    __shared__ float den_s[64];
    int t = threadIdx.x;
    int s0 = blockIdx.x * 64;
    int bh = blockIdx.y;
    int w = t >> 6, l = t & 63, lm16 = l & 15, quad = l >> 4;
    {
        int arow = t >> 2, akoff = (t & 3) * 16;
        const uint4* ga = (const uint4*)(qbf + ((size_t)bh * 4096 + s0 + arow) * 64 + akoff);
        uint4 u0 = ga[0], u1 = ga[1];
        bufA[arow][(akoff >> 3)] = u0; bufA[arow][(akoff >> 3) + 1] = u1;
        float ss = sumsq8(u0) + sumsq8(u1);
        ss += __shfl_xor(ss, 1); ss += __shfl_xor(ss, 2);
        if ((t & 3) == 0) diag_s[arow] = DIAGC * ss;
        uint4 zero = {0, 0, 0, 0};
        for (int row = t; row < 272; row += 256) {
            const uint4* gp = (const uint4*)(projbf + (size_t)row * 64);
            bool bv = row < 266;
#pragma unroll
            for (int i2 = 0; i2 < 8; i2++) bufB[row][i2] = bv ? gp[i2] : zero;
        }
        ks_s[t] = ksum[bh * 272 + t];
        if (t < 16) ks_s[256 + t] = ksum[bh * 272 + 256 + t];
    }
    __syncthreads();
    f32x4 acc[17] = {};
#pragma unroll
    for (int ks = 0; ks < 2; ks++) {
        bf16x8 af = *(const bf16x8*)&bufA[w * 16 + lm16][ks * 4 + quad];
#pragma unroll
        for (int j = 0; j < 17; j++) {
            bf16x8 bfv = *(const bf16x8*)&bufB[j * 16 + lm16][ks * 4 + quad];
            acc[j] = __builtin_amdgcn_mfma_f32_16x16x32_bf16(af, bfv, acc[j], 0, 0, 0);
        }
    }
    int rloc = w * 16 + quad * 4;
    float dg[4];
#pragma unroll
    for (int r = 0; r < 4; r++) dg[r] = diag_s[rloc + r];
    float vmax[4] = {-1e30f, -1e30f, -1e30f, -1e30f};
#pragma unroll
    for (int j = 0; j < 17; j++) {
        int m = j * 16 + lm16;
        bool valid = m < 266;
#pragma unroll
        for (int r = 0; r < 4; r++) {
            float v = acc[j][r] * DN - dg[r];
            acc[j][r] = v;
            if (valid) vmax[r] = fmaxf(vmax[r], v);
        }
    }
#pragma unroll
    for (int m2 = 1; m2 <= 8; m2 <<= 1)
#pragma unroll
        for (int r = 0; r < 4; r++) vmax[r] = fmaxf(vmax[r], __shfl_xor(vmax[r], m2));
    __syncthreads();
    unsigned short* qp_s = (unsigned short*)bufB;   // [64][280]
    float den[4] = {0.f, 0.f, 0.f, 0.f};
#pragma unroll
    for (int j = 0; j < 17; j++) {
        int m = j * 16 + lm16;
        bool valid = m < 266;
#pragma unroll
        for (int r = 0; r < 4; r++) {
            float e = valid ? RATIO * (expf(acc[j][r] - vmax[r]) + FEPS) : 0.f;
            qp_s[(rloc + r) * 280 + m] = f2bf(e);
            den[r] += e * ks_s[m];
        }
    }
#pragma unroll
    for (int m2 = 1; m2 <= 8; m2 <<= 1)
#pragma unroll
        for (int r = 0; r < 4; r++) den[r] += __shfl_xor(den[r], m2);
    if (lm16 == 0) {
#pragma unroll
        for (int r = 0; r < 4; r++) den_s[rloc + r] = den[r];
    }
    __syncthreads();
    uint4* ctx_s = &bufA[0][0];   // [64][5] per k-chunk
    const float* ctxb = ctxT + (size_t)bh * 64 * 272;
    f32x4 oacc[4] = {};
    int ce = t >> 2, cj = t & 3;
    for (int k0 = 0; k0 < 272; k0 += 32) {
        int m = k0 + cj * 8;
        uint4 pk = {0, 0, 0, 0};
        if (m < 272) {
            const float* src = ctxb + (size_t)ce * 272 + m;
            float4 f0 = *(const float4*)(src);
            float4 f1 = *(const float4*)(src + 4);
            pk.x = pack2(f0.x, f0.y); pk.y = pack2(f0.z, f0.w);
            pk.z = pack2(f1.x, f1.y); pk.w = pack2(f1.z, f1.w);
        }
        __syncthreads();
        ctx_s[ce * 5 + cj] = pk;
        __syncthreads();
        bf16x8 af = *(const bf16x8*)&qp_s[(w * 16 + lm16) * 280 + k0 + quad * 8];
#pragma unroll
        for (int jt = 0; jt < 4; jt++) {
            bf16x8 bfv = *(const bf16x8*)&ctx_s[(jt * 16 + lm16) * 5 + quad];
            oacc[jt] = __builtin_amdgcn_mfma_f32_16x16x32_bf16(af, bfv, oacc[jt], 0, 0, 0);
        }
    }
    int b = bh >> 2, h = bh & 3;
#pragma unroll
    for (int jt = 0; jt < 4; jt++) {
        int e = jt * 16 + lm16;
#pragma unroll
        for (int r = 0; r < 4; r++) {
            int sl = w * 16 + quad * 4 + r;
            float v = oacc[jt][r] / den_s[sl];
            abf[((size_t)(b * 4096 + s0 + sl)) * 256 + h * 64 + e] = f2bf(v);
        }
    }
}

// ---------------- pooling tail ----------------
__global__ __launch_bounds__(256) void pool_denom_kernel(
    const float* __restrict__ alpha, float* __restrict__ denomb)
{
    __shared__ float sred[4];
    int b = blockIdx.x, t = threadIdx.x;
    float p = 0.f;
    for (int s = t; s < 4096; s += 256) p += alpha[b * 4096 + s];
    p = wredsum(p);
    if ((t & 63) == 0) sred[t >> 6] = p;
    __syncthreads();
    if (t == 0) denomb[b] = sred[0] + sred[1] + sred[2] + sred[3] + 1e-8f;
}

__global__ __launch_bounds__(256) void pool_out_kernel(
    const float* __restrict__ x, const float* __restrict__ alpha,
    const float* __restrict__ denomb, float* __restrict__ out)
{
    int b = blockIdx.x, chunk = blockIdx.y, t = threadIdx.x;
    float inv = 1.0f / denomb[b];
    float acc = 0.f;
    int s0 = chunk * 128;
    for (int s = s0; s < s0 + 128; s++)
        acc += x[((size_t)(b << 12) + s) * 256 + t] * alpha[(b << 12) + s];
    atomicAdd(&out[b * 256 + t], acc * inv);
}

extern "C" void kernel_launch(void* const* d_in, const int* in_sizes, int n_in,
                              void* d_out, int out_size, void* d_ws, size_t ws_size,
                              hipStream_t stream)
{
    const float* input_embs = (const float*)d_in[0];
    const float* mask  = (const float*)d_in[1];
    const float* pos   = (const float*)d_in[2];
    const float* ln_g  = (const float*)d_in[3];
    const float* ln_b  = (const float*)d_in[4];
    const float* proj  = (const float*)d_in[5];
    const float* Wq = (const float*)d_in[6];  const float* bq = (const float*)d_in[7];
    const float* Wk = (const float*)d_in[8];  const float* bk = (const float*)d_in[9];
    const float* Wv = (const float*)d_in[10]; const float* bv = (const float*)d_in[11];
    const float* Wo = (const float*)d_in[12]; const float* bo = (const float*)d_in[13];
    const float* ln1g = (const float*)d_in[14]; const float* ln1b = (const float*)d_in[15];
    const float* W1 = (const float*)d_in[16]; const float* b1 = (const float*)d_in[17];
    const float* W2 = (const float*)d_in[18]; const float* b2 = (const float*)d_in[19];
    const float* ln2g = (const float*)d_in[20]; const float* ln2b = (const float*)d_in[21];
    const float* p1w = (const float*)d_in[22]; const float* p1b = (const float*)d_in[23];
    const float* p2w = (const float*)d_in[24]; const float* p2b = (const float*)d_in[25];
    float* out = (float*)d_out;
    char* ws = (char*)d_ws;

    size_t off = 0;
    auto alloc = [&](size_t bytes) { size_t o = off; off += WS_ALIGN(bytes); return o; };
    float* xbuf = (float*)(ws + alloc(16384ull * 256 * 4));
    unsigned short* hbf = (unsigned short*)(ws + alloc(16384ull * 256 * 2));   // ln-out / attn-out
    unsigned short* qbf = (unsigned short*)(ws + alloc(16384ull * 256 * 2));
    unsigned short* kbf = (unsigned short*)(ws + alloc(16384ull * 256 * 2));
    unsigned short* vT  = (unsigned short*)(ws + alloc(16384ull * 256 * 2));
    unsigned short* midbf = (unsigned short*)(ws + alloc(16384ull * 1024 * 2)); // FFN mid
    size_t ksum_off = alloc(16ull * 272 * 4);        // ksum..ctxT contiguous, zeroed in phi_kmax
    float* ksum = (float*)(ws + ksum_off);
    float* ctxT = (float*)(ws + alloc(16ull * 64 * 272 * 4));
    float* pmaxb = (float*)(ws + alloc(1024ull * 4));
    float* alphab = (float*)(ws + alloc(16384ull * 4));
    float* pdenom = (float*)(ws + alloc(256));
    unsigned short* Wqt = (unsigned short*)(ws + alloc(4ull * 65536 * 2));
    unsigned short* Wkt = (unsigned short*)(ws + alloc(4ull * 65536 * 2));
    unsigned short* Wvt = (unsigned short*)(ws + alloc(4ull * 65536 * 2));
    unsigned short* Wot = (unsigned short*)(ws + alloc(4ull * 65536 * 2));
    unsigned short* W1t = (unsigned short*)(ws + alloc(4ull * 262144 * 2));
    unsigned short* W2t = (unsigned short*)(ws + alloc(4ull * 262144 * 2));
    unsigned short* projbf = (unsigned short*)(ws + alloc(4ull * 17024 * 2));
    unsigned short* p1t = (unsigned short*)(ws + alloc(65536ull * 2));
    unsigned short* abf = hbf;
    // total ~93 MB (< 256 MiB)

    // ---- weight casts (all layers up front) ----
    cast_transpose4_kernel<<<dim3(8, 8, 16), 256, 0, stream>>>(Wq, Wk, Wv, Wo, Wqt, Wkt, Wvt, Wot);
    cast_transpose_kernel<<<dim3(32, 8, 4), 256, 0, stream>>>(W1, W1t, 256, 1024);
    cast_transpose_kernel<<<dim3(8, 32, 4), 256, 0, stream>>>(W2, W2t, 1024, 256);
    cast_transpose_kernel<<<dim3(8, 8, 1), 256, 0, stream>>>(p1w, p1t, 256, 256);
    cast_row_kernel<<<67, 256, 0, stream>>>((const float4*)proj, (ushort4*)projbf, 17024);

    // ---- x = LN(input + pos); hbf = LN1_0(x) — single fused kernel ----
    add_ln2_kernel<<<16384, 256, 0, stream>>>(input_embs, pos, ln_g, ln_b, ln1g, ln1b, xbuf, hbf);

    for (int i = 0; i < 4; i++) {
        const unsigned short* pj = projbf + (size_t)i * 17024;
        // QKV fused (r9 128x64 tiles)
        qkv_kernel<<<dim3(12, 128), 256, 0, stream>>>(hbf,
            Wqt + (size_t)i * 65536, Wkt + (size_t)i * 65536, Wvt + (size_t)i * 65536,
            bq + i * 256, bk + i * 256, bv + i * 256, qbf, kbf, vT);
        // k stabilizer block-max + zero ksum/ctxT
        phi_kmax_kernel<<<dim3(64, 16), 256, 0, stream>>>(kbf, pj, pmaxb, ksum);
        // fused k-exp + ksum + ctx (inline stab reduce)
        ctx_fused_kernel<<<dim3(5, 16, 8), 256, 0, stream>>>(kbf, vT, pj, pmaxb, ksum, ctxT);
        // fused q-side: dash + exp + denom + attn out (qp stays in LDS)
        phi_q_attn_kernel<<<dim3(64, 16), 256, 0, stream>>>(qbf, pj, ksum, ctxT, abf);
        // Wo + residual + LN2 fused
        gemm_fullrow_kernel<0><<<256, 512, 0, stream>>>(abf, Wot + (size_t)i * 65536,
            bo + i * 256, xbuf, ln2g + i * 256, ln2b + i * 256, hbf,
            nullptr, nullptr, nullptr, nullptr, 256);
        // FFN (r9 128x64 tiles)
        ffn1_kernel<<<dim3(16, 128), 256, 0, stream>>>(hbf, W1t + (size_t)i * 262144,
            b1 + i * 1024, midbf, 1024, 256);
        if (i < 3)
            gemm_fullrow_kernel<0><<<256, 512, 0, stream>>>(midbf, W2t + (size_t)i * 262144,
                b2 + i * 256, xbuf, ln1g + (i + 1) * 256, ln1b + (i + 1) * 256, hbf,
                nullptr, nullptr, nullptr, nullptr, 1024);
        else
            gemm_fullrow_kernel<1><<<256, 512, 0, stream>>>(midbf, W2t + (size_t)i * 262144,
                b2 + i * 256, xbuf, nullptr, nullptr, hbf,
                nullptr, nullptr, nullptr, nullptr, 1024);
    }

    // ---- attention pooling (score fused into GEMM) ----
    gemm_fullrow_kernel<2><<<256, 512, 0, stream>>>(hbf, p1t, p1b, nullptr, nullptr, nullptr,
        nullptr, p2w, p2b, mask, alphab, 256);
    pool_denom_kernel<<<4, 256, 0, stream>>>(alphab, pdenom);
    hipMemsetAsync(d_out, 0, (size_t)out_size * sizeof(float), stream);
    pool_out_kernel<<<dim3(4, 32), 256, 0, stream>>>(xbuf, alphab, pdenom, out);
}